// Round 7
// baseline (1152.743 us; speedup 1.0000x reference)
//
#include <hip/hip_runtime.h>
#include <hip/hip_bf16.h>
#include <stdint.h>

typedef __hip_bfloat16 bf16;
typedef __bf16 bf16x8 __attribute__((ext_vector_type(8)));
typedef float floatx4 __attribute__((ext_vector_type(4)));

#define AS_LDS __attribute__((address_space(3)))
#define AS_GLB __attribute__((address_space(1)))

__device__ __forceinline__ void gload_lds16(const bf16* g, bf16* l) {
    __builtin_amdgcn_global_load_lds((const AS_GLB void*)g, (AS_LDS void*)l, 16, 0, 0);
}

// ---------- dtype probe: *flag = 1 if x is fp32, 0 if bf16 ----------
__global__ void probe_dtype(const float* __restrict__ x, int* __restrict__ flag) {
    __shared__ int cnt;
    if (threadIdx.x == 0) cnt = 0;
    __syncthreads();
    int ok = 0;
    for (int i = threadIdx.x; i < 4096; i += 256) {
        float v = x[i];
        if (v == v && fabsf(v) < 1.0e3f) ok++;
    }
    atomicAdd(&cnt, ok);
    __syncthreads();
    if (threadIdx.x == 0) *flag = (cnt > 2048) ? 1 : 0;
}

// ---------- zero fp32 buffer (for L row-sums) ----------
__global__ __launch_bounds__(256) void zero_f32(float* __restrict__ p, long n) {
    long i = ((long)blockIdx.x * 256 + threadIdx.x) * 4;
    if (i >= n) return;
    *(float4*)&p[i] = (float4){0.f, 0.f, 0.f, 0.f};
}

// ---------- convert raw (fp32 or bf16 per flag) -> canonical bf16 ----------
__global__ __launch_bounds__(256) void convert_to_bf16(
    const void* __restrict__ in, bf16* __restrict__ out, long n,
    const int* __restrict__ flag)
{
    long i = ((long)blockIdx.x * 256 + threadIdx.x) * 8;
    if (i >= n) return;
    bf16 o[8];
    if (*flag) {
        const float* p = (const float*)in + i;
        float4 a = *(const float4*)p;
        float4 b = *(const float4*)(p + 4);
        o[0] = __float2bfloat16(a.x); o[1] = __float2bfloat16(a.y);
        o[2] = __float2bfloat16(a.z); o[3] = __float2bfloat16(a.w);
        o[4] = __float2bfloat16(b.x); o[5] = __float2bfloat16(b.y);
        o[6] = __float2bfloat16(b.z); o[7] = __float2bfloat16(b.w);
    } else {
        *(float4*)o = *(const float4*)((const bf16*)in + i);
    }
    *(float4*)&out[i] = *(float4*)o;
}

// ---------- emit canonical bf16 -> d_out in flag dtype ----------
__global__ __launch_bounds__(256) void emit_out(
    const bf16* __restrict__ in, void* __restrict__ out, long n,
    const int* __restrict__ flag)
{
    long i = ((long)blockIdx.x * 256 + threadIdx.x) * 8;
    if (i >= n) return;
    bf16 v[8];
    *(float4*)v = *(const float4*)&in[i];
    if (*flag) {
        float* o = (float*)out + i;
        float4 a, b;
        a.x = __bfloat162float(v[0]); a.y = __bfloat162float(v[1]);
        a.z = __bfloat162float(v[2]); a.w = __bfloat162float(v[3]);
        b.x = __bfloat162float(v[4]); b.y = __bfloat162float(v[5]);
        b.z = __bfloat162float(v[6]); b.w = __bfloat162float(v[7]);
        *(float4*)o = a;
        *(float4*)(o + 4) = b;
    } else {
        *(float4*)((bf16*)out + i) = *(float4*)v;
    }
}

// ---------- transpose raw-dtype input -> bf16 output ----------
__global__ __launch_bounds__(256) void transpose_any(
    const void* __restrict__ inv, bf16* __restrict__ out,
    int ldin, int ldout, const int* __restrict__ flag)
{
    __shared__ bf16 tile[64][80];
    const int fp32 = *flag;
    const int c0 = blockIdx.x * 64;
    const int r0 = blockIdx.y * 64;
    const int tid = threadIdx.x;
#pragma unroll
    for (int it = 0; it < 2; ++it) {
        int ch = tid + it * 256;
        int r = ch >> 3, c = (ch & 7) * 8;
        long eidx = (long)(r0 + r) * ldin + (c0 + c);
        if (fp32) {
            const float* p = (const float*)inv + eidx;
            float4 a = *(const float4*)p;
            float4 b = *(const float4*)(p + 4);
            bf16 o[8];
            o[0] = __float2bfloat16(a.x); o[1] = __float2bfloat16(a.y);
            o[2] = __float2bfloat16(a.z); o[3] = __float2bfloat16(a.w);
            o[4] = __float2bfloat16(b.x); o[5] = __float2bfloat16(b.y);
            o[6] = __float2bfloat16(b.z); o[7] = __float2bfloat16(b.w);
            *(float4*)&tile[r][c] = *(float4*)o;
        } else {
            *(float4*)&tile[r][c] = *(const float4*)((const bf16*)inv + eidx);
        }
    }
    __syncthreads();
#pragma unroll
    for (int it = 0; it < 2; ++it) {
        int ch = tid + it * 256;
        int oc = ch >> 3, rb = (ch & 7) * 8;
        bf16 tmp[8];
#pragma unroll
        for (int i = 0; i < 8; ++i) tmp[i] = tile[rb + i][oc];
        *(float4*)&out[(long)(c0 + oc) * ldout + r0 + rb] = *(float4*)tmp;
    }
}

// ---------- pure-bf16 transpose (workspace-internal, for V) ----------
__global__ __launch_bounds__(256) void transpose_bf16(
    const bf16* __restrict__ in, bf16* __restrict__ out,
    int ldin, int ldout,
    int nz1, long in_z1, long out_z1, long in_z2, long out_z2)
{
    __shared__ bf16 tile[64][80];
    const int z = blockIdx.z;
    const int z1 = z % nz1, z2 = z / nz1;
    in  += (long)z1 * in_z1 + (long)z2 * in_z2;
    out += (long)z1 * out_z1 + (long)z2 * out_z2;
    const int c0 = blockIdx.x * 64;
    const int r0 = blockIdx.y * 64;
    const int tid = threadIdx.x;
#pragma unroll
    for (int it = 0; it < 2; ++it) {
        int ch = tid + it * 256;
        int r = ch >> 3, c = (ch & 7) * 8;
        *(float4*)&tile[r][c] = *(const float4*)&in[(long)(r0 + r) * ldin + c0 + c];
    }
    __syncthreads();
#pragma unroll
    for (int it = 0; it < 2; ++it) {
        int ch = tid + it * 256;
        int oc = ch >> 3, rb = (ch & 7) * 8;
        bf16 tmp[8];
#pragma unroll
        for (int i = 0; i < 8; ++i) tmp[i] = tile[rb + i][oc];
        *(float4*)&out[(long)(c0 + oc) * ldout + r0 + rb] = *(float4*)tmp;
    }
}

// ---------- GEMM (bf16 in/out, fp32 acc) --------------------------------
// mode 0: C = (acc + bias) * (col<qcols ? scale : 1)
// mode 1: C = exp(acc); row-sums atomically added into Lsum[zz*lz + row]
// mode 2: C += acc   (accumulate; tier-D fallback)
__global__ __launch_bounds__(256) void gemm_bt(
    const bf16* __restrict__ A, const bf16* __restrict__ Bt,
    bf16* __restrict__ C, const bf16* __restrict__ bias,
    int lda, int ldb, int ldc,
    long az, long bz, long cz, int K, float scale, int qcols,
    int mode, float* __restrict__ Lsum, int lz)
{
    __shared__ bf16 As[128 * 64];
    __shared__ bf16 Bs[128 * 64];

    const int tid  = threadIdx.x;
    const int lane = tid & 63;
    const int wave = tid >> 6;
    const int wx = wave & 1;
    const int wy = wave >> 1;
    const long zz = blockIdx.z;
    A  += zz * az;
    Bt += zz * bz;
    C  += zz * cz;
    const int m0 = blockIdx.y * 128;
    const int n0 = blockIdx.x * 128;

    const int lm = lane & 15;
    const int kq = (lane >> 4) * 8;

    floatx4 acc[4][4];
#pragma unroll
    for (int i = 0; i < 4; ++i)
#pragma unroll
        for (int j = 0; j < 4; ++j)
            acc[i][j] = (floatx4){0.f, 0.f, 0.f, 0.f};

    for (int kt = 0; kt < K; kt += 64) {
        __syncthreads();
#pragma unroll
        for (int it = 0; it < 4; ++it) {
            int ch = tid + it * 256;
            int r = ch >> 3;
            int c = (ch & 7) * 8;
            gload_lds16(A  + (long)(m0 + r) * lda + (kt + c), &As[ch * 8]);
            gload_lds16(Bt + (long)(n0 + r) * ldb + (kt + c), &Bs[ch * 8]);
        }
        __syncthreads();
#pragma unroll
        for (int kk = 0; kk < 64; kk += 32) {
            bf16x8 af[4], bfv[4];
#pragma unroll
            for (int i = 0; i < 4; ++i)
                af[i] = *(const bf16x8*)&As[(wy * 64 + i * 16 + lm) * 64 + kk + kq];
#pragma unroll
            for (int j = 0; j < 4; ++j)
                bfv[j] = *(const bf16x8*)&Bs[(wx * 64 + j * 16 + lm) * 64 + kk + kq];
#pragma unroll
            for (int i = 0; i < 4; ++i)
#pragma unroll
                for (int j = 0; j < 4; ++j)
                    acc[i][j] = __builtin_amdgcn_mfma_f32_16x16x32_bf16(
                        af[i], bfv[j], acc[i][j], 0, 0, 0);
        }
    }

    const int cr = (lane >> 4) * 4;
    if (mode == 1) {
        // exp epilogue + per-row sum: lanes with same (lane>>4) share 4 rows;
        // shfl_xor over lm bits (0..3) totals across the 16 col-lanes.
#pragma unroll
        for (int i = 0; i < 4; ++i) {
#pragma unroll
            for (int r = 0; r < 4; ++r) {
                int row = m0 + wy * 64 + i * 16 + cr + r;
                float s = 0.f;
#pragma unroll
                for (int j = 0; j < 4; ++j) {
                    int col = n0 + wx * 64 + j * 16 + lm;
                    float e = __expf(acc[i][j][r]);
                    C[(long)row * ldc + col] = __float2bfloat16(e);
                    s += e;
                }
                s += __shfl_xor(s, 1); s += __shfl_xor(s, 2);
                s += __shfl_xor(s, 4); s += __shfl_xor(s, 8);
                if (lm == 0) atomicAdd(&Lsum[zz * (long)lz + row], s);
            }
        }
    } else {
#pragma unroll
        for (int j = 0; j < 4; ++j) {
            int col = n0 + wx * 64 + j * 16 + lm;
            float bv = (mode == 0 && bias) ? __bfloat162float(bias[col]) : 0.f;
            float sc = (col < qcols) ? scale : 1.0f;
#pragma unroll
            for (int i = 0; i < 4; ++i) {
#pragma unroll
                for (int r = 0; r < 4; ++r) {
                    int row = m0 + wy * 64 + i * 16 + cr + r;
                    long idx = (long)row * ldc + col;
                    float v;
                    if (mode == 2) v = acc[i][j][r] + __bfloat162float(C[idx]);
                    else           v = (acc[i][j][r] + bv) * sc;
                    C[idx] = __float2bfloat16(v);
                }
            }
        }
    }
}

// ---------- split-K GEMM, bf16 partials ---------------------------------
// z decomposed: ks = z % nsk (k-slice), zh = z / nsk (head/batch slice).
// P[zh-slice via pz][ks via skStride][row*ldp + col].
__global__ __launch_bounds__(256) void gemm_bt_splitk(
    const bf16* __restrict__ A, const bf16* __restrict__ Bt,
    bf16* __restrict__ P, int lda, int ldb, int ldp,
    long az, long bz, long pz, long skStride, int nsk, int Kc)
{
    __shared__ bf16 As[128 * 64];
    __shared__ bf16 Bs[128 * 64];

    const int tid  = threadIdx.x;
    const int lane = tid & 63;
    const int wave = tid >> 6;
    const int wx = wave & 1;
    const int wy = wave >> 1;
    const int zz = blockIdx.z;
    const int ks = zz % nsk;
    const int zh = zz / nsk;
    A  += (long)zh * az;
    Bt += (long)zh * bz;
    bf16* Pz = P + (long)zh * pz + (long)ks * skStride;
    const int m0 = blockIdx.y * 128;
    const int n0 = blockIdx.x * 128;
    const int k0 = ks * Kc;

    const int lm = lane & 15;
    const int kq = (lane >> 4) * 8;

    floatx4 acc[4][4];
#pragma unroll
    for (int i = 0; i < 4; ++i)
#pragma unroll
        for (int j = 0; j < 4; ++j)
            acc[i][j] = (floatx4){0.f, 0.f, 0.f, 0.f};

    for (int kt = k0; kt < k0 + Kc; kt += 64) {
        __syncthreads();
#pragma unroll
        for (int it = 0; it < 4; ++it) {
            int ch = tid + it * 256;
            int r = ch >> 3;
            int c = (ch & 7) * 8;
            gload_lds16(A  + (long)(m0 + r) * lda + (kt + c), &As[ch * 8]);
            gload_lds16(Bt + (long)(n0 + r) * ldb + (kt + c), &Bs[ch * 8]);
        }
        __syncthreads();
#pragma unroll
        for (int kk = 0; kk < 64; kk += 32) {
            bf16x8 af[4], bfv[4];
#pragma unroll
            for (int i = 0; i < 4; ++i)
                af[i] = *(const bf16x8*)&As[(wy * 64 + i * 16 + lm) * 64 + kk + kq];
#pragma unroll
            for (int j = 0; j < 4; ++j)
                bfv[j] = *(const bf16x8*)&Bs[(wx * 64 + j * 16 + lm) * 64 + kk + kq];
#pragma unroll
            for (int i = 0; i < 4; ++i)
#pragma unroll
                for (int j = 0; j < 4; ++j)
                    acc[i][j] = __builtin_amdgcn_mfma_f32_16x16x32_bf16(
                        af[i], bfv[j], acc[i][j], 0, 0, 0);
        }
    }

    const int cr = (lane >> 4) * 4;
#pragma unroll
    for (int j = 0; j < 4; ++j) {
        int col = n0 + wx * 64 + j * 16 + lm;
#pragma unroll
        for (int i = 0; i < 4; ++i)
#pragma unroll
            for (int r = 0; r < 4; ++r) {
                int row = m0 + wy * 64 + i * 16 + cr + r;
                Pz[(long)row * ldp + col] = __float2bfloat16(acc[i][j][r]);
            }
    }
}

// ---------- reduce bf16 split-K partials + bias -> bf16 (8-wide) ----------
__global__ __launch_bounds__(256) void reduce_splitk(
    const bf16* __restrict__ P, const bf16* __restrict__ bias,
    bf16* __restrict__ Out, long MN, int N, int SK)
{
    long i = ((long)blockIdx.x * 256 + threadIdx.x) * 8;
    if (i >= MN) return;
    float s[8];
    if (bias) {
        bf16 bb[8];
        *(float4*)bb = *(const float4*)&bias[i & (N - 1)];
#pragma unroll
        for (int k = 0; k < 8; ++k) s[k] = __bfloat162float(bb[k]);
    } else {
#pragma unroll
        for (int k = 0; k < 8; ++k) s[k] = 0.f;
    }
    for (int z = 0; z < SK; ++z) {
        bf16 a[8];
        *(float4*)a = *(const float4*)&P[(long)z * MN + i];
#pragma unroll
        for (int k = 0; k < 8; ++k) s[k] += __bfloat162float(a[k]);
    }
    bf16 o[8];
#pragma unroll
    for (int k = 0; k < 8; ++k) o[k] = __float2bfloat16(s[k]);
    *(float4*)&Out[i] = *(float4*)o;
}

// ---------- reduce PV split-K(2) partials, normalize by L ----------------
// P layout: [2][T=2048, HE=4096] bf16; L[h*2048 + t]; Out[t, h*512+e].
__global__ __launch_bounds__(256) void reduce_pv(
    const bf16* __restrict__ P, const float* __restrict__ L,
    bf16* __restrict__ Out, long MN)
{
    long i = ((long)blockIdx.x * 256 + threadIdx.x) * 8;
    if (i >= MN) return;
    long t  = i >> 12;            // / 4096
    int col = (int)(i & 4095);
    int h   = col >> 9;           // / 512
    float inv = 1.0f / L[(long)h * 2048 + t];
    bf16 a[8], b[8], o[8];
    *(float4*)a = *(const float4*)&P[i];
    *(float4*)b = *(const float4*)&P[MN + i];
#pragma unroll
    for (int k = 0; k < 8; ++k)
        o[k] = __float2bfloat16((__bfloat162float(a[k]) + __bfloat162float(b[k])) * inv);
    *(float4*)&Out[i] = *(float4*)o;
}

// ---------- in-place softmax over rows of 2048 bf16 (fallback tiers) -----
__global__ __launch_bounds__(256) void softmax_rows2048(bf16* __restrict__ S)
{
    __shared__ float red[8];
    const long row = blockIdx.x;
    bf16* p = S + row * 2048;
    const int tid = threadIdx.x;
    float4 raw = *(const float4*)&p[tid * 8];
    bf16 vb[8];
    *(float4*)vb = raw;
    float v[8];
#pragma unroll
    for (int i = 0; i < 8; ++i) v[i] = __bfloat162float(vb[i]);
    float m = v[0];
#pragma unroll
    for (int i = 1; i < 8; ++i) m = fmaxf(m, v[i]);
#pragma unroll
    for (int o = 32; o > 0; o >>= 1) m = fmaxf(m, __shfl_xor(m, o));
    if ((tid & 63) == 0) red[tid >> 6] = m;
    __syncthreads();
    m = fmaxf(fmaxf(red[0], red[1]), fmaxf(red[2], red[3]));
    float s = 0.f;
#pragma unroll
    for (int i = 0; i < 8; ++i) { v[i] = __expf(v[i] - m); s += v[i]; }
#pragma unroll
    for (int o = 32; o > 0; o >>= 1) s += __shfl_xor(s, o);
    if ((tid & 63) == 0) red[4 + (tid >> 6)] = s;
    __syncthreads();
    s = (red[4] + red[5]) + (red[6] + red[7]);
    float inv = 1.f / s;
#pragma unroll
    for (int i = 0; i < 8; ++i) vb[i] = __float2bfloat16(v[i] * inv);
    *(float4*)&p[tid * 8] = *(float4*)vb;
}

extern "C" void kernel_launch(void* const* d_in, const int* in_sizes, int n_in,
                              void* d_out, int out_size, void* d_ws, size_t ws_size,
                              hipStream_t stream)
{
    const int Bb = 4, T = 2048, E = 512, H = 8;
    const int HE = H * E;            // 4096
    const int N3 = 3 * HE;           // 12288
    const int M  = Bb * T;           // 8192
    const long NX = (long)M * E;     // 4,194,304

    // ---- size-signature input assignment (order-robust) ----
    const void* xr = nullptr;
    const void* Wr[4] = {nullptr, nullptr, nullptr, nullptr};
    const void* br[3] = {nullptr, nullptr, nullptr};
    const void* bor = nullptr;
    int nw = 0, nb = 0;
    for (int i = 0; i < n_in; ++i) {
        int s = in_sizes[i];
        if      (s == (int)NX)      xr = d_in[i];
        else if (s == E * HE)       { if (nw < 4) Wr[nw++] = d_in[i]; }
        else if (s == HE)           { if (nb < 3) br[nb++] = d_in[i]; }
        else if (s == E)            bor = d_in[i];
    }
    if (!xr || nw < 4 || nb < 3 || !bor) {
        xr = d_in[0]; Wr[0] = d_in[1]; br[0] = d_in[2]; Wr[1] = d_in[3];
        br[1] = d_in[4]; Wr[2] = d_in[5]; br[2] = d_in[6]; Wr[3] = d_in[7];
        bor = d_in[8];
    }

    const float qscale = 0.04419417382415922f;  // 1/sqrt(512)
    const int   QC = 1 << 30;
    dim3 blk(256);

    // ---- workspace layout (bf16 elements) ----
    bf16* pool = (bf16*)d_ws;
    int*  flag = (int*)(void*)pool;
    bf16* xc   = pool + 8;
    bf16* bqc  = xc  + NX;     // bq|bk|bv contiguous (stacked bias [12288])
    bf16* bkc  = bqc + HE;
    bf16* bvc  = bkc + HE;
    bf16* boc  = bvc + HE;
    bf16* WqT  = boc + E;      // WqT|WkT|WvT contiguous (stacked Bt [12288,512])
    const size_t w2m = (size_t)E * HE;
    bf16* WkT  = WqT + w2m;
    bf16* WvT  = WkT + w2m;
    bf16* WoT  = WvT + w2m;
    bf16* Ofin = WoT + w2m;
    float* Lall = (float*)(Ofin + NX);          // 4*8*2048 fp32 = 256 KB
    const long nL = (long)Bb * H * T;           // 65536 floats
    bf16* p0   = Ofin + NX + 2 * nL;            // tier region

    const size_t wsE    = ws_size / sizeof(bf16);
    const size_t fixedE = (size_t)(p0 - pool);
    const size_t wQKV  = (size_t)T * N3;      // 25.17M el
    const size_t wBat  = (size_t)T * HE;      // 8.39M el
    const size_t wHd   = (size_t)T * E;       // 1.05M el
    const size_t sAll  = (size_t)H * T * T;   // 33.55M el
    const size_t sOne  = (size_t)T * T;
    const size_t wBig  = (size_t)M * HE;      // 33.55M el
    const size_t needB2 = fixedE + wQKV + wBat + sAll + wBig;  // ~235 MB
    const size_t needB  = fixedE + wQKV + 2 * wBat + sAll;     // ~185 MB
    const size_t needC  = fixedE + 5 * wBat + sOne;
    const size_t needD  = fixedE + 5 * wHd  + sOne;
    if (wsE < needD) return;

    // ---- stage 0: dtype probe + canonicalize + L zero ----
    probe_dtype<<<dim3(1), blk, 0, stream>>>((const float*)xr, flag);
    zero_f32<<<dim3((unsigned)((nL / 4 + 255) / 256)), blk, 0, stream>>>(Lall, nL);
    convert_to_bf16<<<dim3((unsigned)((NX / 8 + 255) / 256)), blk, 0, stream>>>(
        xr, xc, NX, flag);
    convert_to_bf16<<<dim3(2), blk, 0, stream>>>(br[0], bqc, HE, flag);
    convert_to_bf16<<<dim3(2), blk, 0, stream>>>(br[1], bkc, HE, flag);
    convert_to_bf16<<<dim3(2), blk, 0, stream>>>(br[2], bvc, HE, flag);
    convert_to_bf16<<<dim3(1), blk, 0, stream>>>(bor, boc, E, flag);
    transpose_any<<<dim3(HE / 64, E / 64, 1), blk, 0, stream>>>(Wr[0], WqT, HE, E, flag);
    transpose_any<<<dim3(HE / 64, E / 64, 1), blk, 0, stream>>>(Wr[1], WkT, HE, E, flag);
    transpose_any<<<dim3(HE / 64, E / 64, 1), blk, 0, stream>>>(Wr[2], WvT, HE, E, flag);
    transpose_any<<<dim3(E / 64, HE / 64, 1), blk, 0, stream>>>(Wr[3], WoT, E, HE, flag);

    if (wsE >= needB2) {
        // ---- Tier B2: softmax-free attention, split-K PV + out-proj ----
        bf16* QKVb = p0;                 // [t, 12288]; later aliased for P
        bf16* Vtb  = QKVb + wQKV;        // [h,e,t]
        bf16* S    = Vtb + wBat;         // exp(scores) [h,t,s]
        bf16* Oatt = S + sAll;           // O_all [M, HE]

        for (int b = 0; b < Bb; ++b) {
            const bf16* xb = xc + (size_t)b * T * E;
            float* Lb = Lall + (long)b * H * T;
            // merged QKV projection
            gemm_bt<<<dim3(N3 / 128, T / 128, 1), blk, 0, stream>>>(
                xb, WqT, QKVb, bqc, E, E, N3, 0, 0, 0, E, qscale, HE,
                0, nullptr, 0);
            transpose_bf16<<<dim3(E / 64, T / 64, H), blk, 0, stream>>>(
                QKVb + 2 * HE, Vtb, N3, T, H, (long)E, (long)E * T, 0, 0);
            // QK: exp epilogue + row-sums into Lb
            gemm_bt<<<dim3(T / 128, T / 128, H), blk, 0, stream>>>(
                QKVb, QKVb + HE, S, nullptr, N3, N3, T,
                (long)E, (long)E, (long)T * T, E, 1.f, QC, 1, Lb, T);
            // PV: split-K=2, bf16 partials alias QKVb (dead now), 33.5 MB
            gemm_bt_splitk<<<dim3(E / 128, T / 128, 2 * H), blk, 0, stream>>>(
                S, Vtb, QKVb, T, T, HE,
                (long)T * T, (long)E * T, (long)E, (long)T * HE, 2, T / 2);
            reduce_pv<<<dim3((unsigned)(((long)T * HE / 8 + 255) / 256)), blk, 0, stream>>>(
                QKVb, Lb, Oatt + (size_t)b * T * HE, (long)T * HE);
        }
        // out-proj: split-K=4, bf16 partials alias QKVb
        gemm_bt_splitk<<<dim3(E / 128, M / 128, 4), blk, 0, stream>>>(
            Oatt, WoT, QKVb, HE, HE, E, 0, 0, 0, (long)M * E, 4, HE / 4);
        reduce_splitk<<<dim3((unsigned)((NX / 8 + 255) / 256)), blk, 0, stream>>>(
            QKVb, boc, Ofin, NX, E, 4);
    } else if (wsE >= needB) {
        // ---- Tier B fallback: round-6 flow (softmax path) ----
        bf16* QKVb = p0;
        bf16* Vtb  = QKVb + wQKV;
        bf16* Oatt = Vtb + wBat;
        bf16* S    = Oatt + wBat;

        for (int b = 0; b < Bb; ++b) {
            const bf16* xb = xc + (size_t)b * T * E;
            gemm_bt<<<dim3(N3 / 128, T / 128, 1), blk, 0, stream>>>(
                xb, WqT, QKVb, bqc, E, E, N3, 0, 0, 0, E, qscale, HE,
                0, nullptr, 0);
            transpose_bf16<<<dim3(E / 64, T / 64, H), blk, 0, stream>>>(
                QKVb + 2 * HE, Vtb, N3, T, H, (long)E, (long)E * T, 0, 0);
            gemm_bt<<<dim3(T / 128, T / 128, H), blk, 0, stream>>>(
                QKVb, QKVb + HE, S, nullptr, N3, N3, T,
                (long)E, (long)E, (long)T * T, E, 1.f, QC, 0, nullptr, 0);
            softmax_rows2048<<<dim3(H * T, 1, 1), blk, 0, stream>>>(S);
            gemm_bt<<<dim3(E / 128, T / 128, H), blk, 0, stream>>>(
                S, Vtb, Oatt, nullptr, T, T, HE,
                (long)T * T, (long)E * T, (long)E, T, 1.f, QC, 0, nullptr, 0);
            gemm_bt_splitk<<<dim3(E / 128, T / 128, 8), blk, 0, stream>>>(
                Oatt, WoT, (bf16*)S, HE, HE, E, 0, 0, 0, (long)T * E, 8, HE / 8);
            reduce_splitk<<<dim3((unsigned)(((long)T * E / 8 + 255) / 256)), blk, 0, stream>>>(
                (bf16*)S, boc, Ofin + (size_t)b * T * E, (long)T * E, E, 8);
        }
    } else if (wsE >= needC) {
        // ---- Tier C fallback ----
        bf16* Qb  = p0;
        bf16* Kb  = Qb  + wBat;
        bf16* Vb  = Kb  + wBat;
        bf16* Vtb = Vb  + wBat;
        bf16* Ob  = Vtb + wBat;
        bf16* S   = Ob  + wBat;

        for (int b = 0; b < Bb; ++b) {
            const bf16* xb = xc + (size_t)b * T * E;
            gemm_bt<<<dim3(HE / 128, T / 128, 1), blk, 0, stream>>>(
                xb, WqT, Qb, bqc, E, E, HE, 0, 0, 0, E, qscale, QC, 0, nullptr, 0);
            gemm_bt<<<dim3(HE / 128, T / 128, 1), blk, 0, stream>>>(
                xb, WkT, Kb, bkc, E, E, HE, 0, 0, 0, E, 1.f, QC, 0, nullptr, 0);
            gemm_bt<<<dim3(HE / 128, T / 128, 1), blk, 0, stream>>>(
                xb, WvT, Vb, bvc, E, E, HE, 0, 0, 0, E, 1.f, QC, 0, nullptr, 0);
            transpose_bf16<<<dim3(E / 64, T / 64, H), blk, 0, stream>>>(
                Vb, Vtb, HE, T, H, (long)E, (long)E * T, 0, 0);
            for (int h = 0; h < H; ++h) {
                gemm_bt<<<dim3(T / 128, T / 128, 1), blk, 0, stream>>>(
                    Qb + (size_t)h * E, Kb + (size_t)h * E, S, nullptr,
                    HE, HE, T, 0, 0, 0, E, 1.f, QC, 0, nullptr, 0);
                softmax_rows2048<<<dim3(T, 1, 1), blk, 0, stream>>>(S);
                gemm_bt<<<dim3(E / 128, T / 128, 1), blk, 0, stream>>>(
                    S, Vtb + (size_t)h * E * T, Ob + (size_t)h * E, nullptr,
                    T, T, HE, 0, 0, 0, T, 1.f, QC, 0, nullptr, 0);
            }
            gemm_bt<<<dim3(E / 128, T / 128, 1), blk, 0, stream>>>(
                Ob, WoT, Ofin + (size_t)b * T * E, boc,
                HE, HE, E, 0, 0, 0, HE, 1.f, QC, 0, nullptr, 0);
        }
    } else {
        // ---- Tier D fallback ----
        bf16* Qh  = p0;
        bf16* Kh  = Qh  + wHd;
        bf16* Vh  = Kh  + wHd;
        bf16* Vth = Vh  + wHd;
        bf16* Oh  = Vth + wHd;
        bf16* S   = Oh  + wHd;

        for (int b = 0; b < Bb; ++b) {
            const bf16* xb = xc + (size_t)b * T * E;
            bf16* outb = Ofin + (size_t)b * T * E;
            for (int h = 0; h < H; ++h) {
                const size_t hw = (size_t)h * E * E;
                gemm_bt<<<dim3(E / 128, T / 128, 1), blk, 0, stream>>>(
                    xb, WqT + hw, Qh, bqc + (size_t)h * E, E, E, E,
                    0, 0, 0, E, qscale, QC, 0, nullptr, 0);
                gemm_bt<<<dim3(E / 128, T / 128, 1), blk, 0, stream>>>(
                    xb, WkT + hw, Kh, bkc + (size_t)h * E, E, E, E,
                    0, 0, 0, E, 1.f, QC, 0, nullptr, 0);
                gemm_bt<<<dim3(E / 128, T / 128, 1), blk, 0, stream>>>(
                    xb, WvT + hw, Vh, bvc + (size_t)h * E, E, E, E,
                    0, 0, 0, E, 1.f, QC, 0, nullptr, 0);
                transpose_bf16<<<dim3(E / 64, T / 64, 1), blk, 0, stream>>>(
                    Vh, Vth, E, T, 1, 0, 0, 0, 0);
                gemm_bt<<<dim3(T / 128, T / 128, 1), blk, 0, stream>>>(
                    Qh, Kh, S, nullptr, E, E, T, 0, 0, 0, E, 1.f, QC, 0, nullptr, 0);
                softmax_rows2048<<<dim3(T, 1, 1), blk, 0, stream>>>(S);
                gemm_bt<<<dim3(E / 128, T / 128, 1), blk, 0, stream>>>(
                    S, Vth, Oh, nullptr, T, T, E, 0, 0, 0, T, 1.f, QC, 0, nullptr, 0);
                gemm_bt<<<dim3(E / 128, T / 128, 1), blk, 0, stream>>>(
                    Oh, WoT + (size_t)h * E, outb, (h == 0) ? boc : nullptr,
                    E, HE, E, 0, 0, 0, E, 1.f, QC, (h == 0) ? 0 : 2, nullptr, 0);
            }
        }
    }

    // ---- emit in the probed dtype ----
    emit_out<<<dim3((unsigned)((NX / 8 + 255) / 256)), blk, 0, stream>>>(
        Ofin, d_out, NX, flag);
}

// Round 8
// 994.734 us; speedup vs baseline: 1.1588x; 1.1588x over previous
//
#include <hip/hip_runtime.h>
#include <hip/hip_bf16.h>
#include <stdint.h>

typedef __hip_bfloat16 bf16;
typedef __bf16 bf16x8 __attribute__((ext_vector_type(8)));
typedef float floatx4 __attribute__((ext_vector_type(4)));

#define AS_LDS __attribute__((address_space(3)))
#define AS_GLB __attribute__((address_space(1)))

__device__ __forceinline__ void gload_lds16(const bf16* g, bf16* l) {
    __builtin_amdgcn_global_load_lds((const AS_GLB void*)g, (AS_LDS void*)l, 16, 0, 0);
}

// ---------- dtype probe: *flag = 1 if x is fp32, 0 if bf16 ----------
__global__ void probe_dtype(const float* __restrict__ x, int* __restrict__ flag) {
    __shared__ int cnt;
    if (threadIdx.x == 0) cnt = 0;
    __syncthreads();
    int ok = 0;
    for (int i = threadIdx.x; i < 4096; i += 256) {
        float v = x[i];
        if (v == v && fabsf(v) < 1.0e3f) ok++;
    }
    atomicAdd(&cnt, ok);
    __syncthreads();
    if (threadIdx.x == 0) *flag = (cnt > 2048) ? 1 : 0;
}

// ---------- convert raw (fp32 or bf16 per flag) -> canonical bf16 ----------
__global__ __launch_bounds__(256) void convert_to_bf16(
    const void* __restrict__ in, bf16* __restrict__ out, long n,
    const int* __restrict__ flag)
{
    long i = ((long)blockIdx.x * 256 + threadIdx.x) * 8;
    if (i >= n) return;
    bf16 o[8];
    if (*flag) {
        const float* p = (const float*)in + i;
        float4 a = *(const float4*)p;
        float4 b = *(const float4*)(p + 4);
        o[0] = __float2bfloat16(a.x); o[1] = __float2bfloat16(a.y);
        o[2] = __float2bfloat16(a.z); o[3] = __float2bfloat16(a.w);
        o[4] = __float2bfloat16(b.x); o[5] = __float2bfloat16(b.y);
        o[6] = __float2bfloat16(b.z); o[7] = __float2bfloat16(b.w);
    } else {
        *(float4*)o = *(const float4*)((const bf16*)in + i);
    }
    *(float4*)&out[i] = *(float4*)o;
}

// ---------- emit canonical bf16 -> d_out in flag dtype ----------
__global__ __launch_bounds__(256) void emit_out(
    const bf16* __restrict__ in, void* __restrict__ out, long n,
    const int* __restrict__ flag)
{
    long i = ((long)blockIdx.x * 256 + threadIdx.x) * 8;
    if (i >= n) return;
    bf16 v[8];
    *(float4*)v = *(const float4*)&in[i];
    if (*flag) {
        float* o = (float*)out + i;
        float4 a, b;
        a.x = __bfloat162float(v[0]); a.y = __bfloat162float(v[1]);
        a.z = __bfloat162float(v[2]); a.w = __bfloat162float(v[3]);
        b.x = __bfloat162float(v[4]); b.y = __bfloat162float(v[5]);
        b.z = __bfloat162float(v[6]); b.w = __bfloat162float(v[7]);
        *(float4*)o = a;
        *(float4*)(o + 4) = b;
    } else {
        *(float4*)((bf16*)out + i) = *(float4*)v;
    }
}

// ---------- transpose raw-dtype input -> bf16 output ----------
__global__ __launch_bounds__(256) void transpose_any(
    const void* __restrict__ inv, bf16* __restrict__ out,
    int ldin, int ldout, const int* __restrict__ flag)
{
    __shared__ bf16 tile[64][80];
    const int fp32 = *flag;
    const int c0 = blockIdx.x * 64;
    const int r0 = blockIdx.y * 64;
    const int tid = threadIdx.x;
#pragma unroll
    for (int it = 0; it < 2; ++it) {
        int ch = tid + it * 256;
        int r = ch >> 3, c = (ch & 7) * 8;
        long eidx = (long)(r0 + r) * ldin + (c0 + c);
        if (fp32) {
            const float* p = (const float*)inv + eidx;
            float4 a = *(const float4*)p;
            float4 b = *(const float4*)(p + 4);
            bf16 o[8];
            o[0] = __float2bfloat16(a.x); o[1] = __float2bfloat16(a.y);
            o[2] = __float2bfloat16(a.z); o[3] = __float2bfloat16(a.w);
            o[4] = __float2bfloat16(b.x); o[5] = __float2bfloat16(b.y);
            o[6] = __float2bfloat16(b.z); o[7] = __float2bfloat16(b.w);
            *(float4*)&tile[r][c] = *(float4*)o;
        } else {
            *(float4*)&tile[r][c] = *(const float4*)((const bf16*)inv + eidx);
        }
    }
    __syncthreads();
#pragma unroll
    for (int it = 0; it < 2; ++it) {
        int ch = tid + it * 256;
        int oc = ch >> 3, rb = (ch & 7) * 8;
        bf16 tmp[8];
#pragma unroll
        for (int i = 0; i < 8; ++i) tmp[i] = tile[rb + i][oc];
        *(float4*)&out[(long)(c0 + oc) * ldout + r0 + rb] = *(float4*)tmp;
    }
}

// ---------- pure-bf16 transpose (workspace-internal, for V) ----------
__global__ __launch_bounds__(256) void transpose_bf16(
    const bf16* __restrict__ in, bf16* __restrict__ out,
    int ldin, int ldout,
    int nz1, long in_z1, long out_z1, long in_z2, long out_z2)
{
    __shared__ bf16 tile[64][80];
    const int z = blockIdx.z;
    const int z1 = z % nz1, z2 = z / nz1;
    in  += (long)z1 * in_z1 + (long)z2 * in_z2;
    out += (long)z1 * out_z1 + (long)z2 * out_z2;
    const int c0 = blockIdx.x * 64;
    const int r0 = blockIdx.y * 64;
    const int tid = threadIdx.x;
#pragma unroll
    for (int it = 0; it < 2; ++it) {
        int ch = tid + it * 256;
        int r = ch >> 3, c = (ch & 7) * 8;
        *(float4*)&tile[r][c] = *(const float4*)&in[(long)(r0 + r) * ldin + c0 + c];
    }
    __syncthreads();
#pragma unroll
    for (int it = 0; it < 2; ++it) {
        int ch = tid + it * 256;
        int oc = ch >> 3, rb = (ch & 7) * 8;
        bf16 tmp[8];
#pragma unroll
        for (int i = 0; i < 8; ++i) tmp[i] = tile[rb + i][oc];
        *(float4*)&out[(long)(c0 + oc) * ldout + r0 + rb] = *(float4*)tmp;
    }
}

// ---------- GEMM (bf16 in/out, fp32 acc), templated epilogue -------------
// MODE 0: C = (acc + bias) * (col<qcols ? scale : 1)
// MODE 1: C = exp(acc)                      (QK scores -> unnormalized weights)
// MODE 2: C += acc                          (tier-D accumulate)
// MODE 3: C = acc / L,  L = row-sum of A computed via MFMA vs ones-fragment
//         (valid because the K-loop spans the full row: K == row length)
template <int MODE>
__global__ __launch_bounds__(256) void gemm_bt(
    const bf16* __restrict__ A, const bf16* __restrict__ Bt,
    bf16* __restrict__ C, const bf16* __restrict__ bias,
    int lda, int ldb, int ldc,
    long az, long bz, long cz, int K, float scale, int qcols)
{
    __shared__ bf16 As[128 * 64];
    __shared__ bf16 Bs[128 * 64];

    const int tid  = threadIdx.x;
    const int lane = tid & 63;
    const int wave = tid >> 6;
    const int wx = wave & 1;
    const int wy = wave >> 1;
    const long zz = blockIdx.z;
    A  += zz * az;
    Bt += zz * bz;
    C  += zz * cz;
    const int m0 = blockIdx.y * 128;
    const int n0 = blockIdx.x * 128;

    const int lm = lane & 15;
    const int kq = (lane >> 4) * 8;

    floatx4 acc[4][4];
#pragma unroll
    for (int i = 0; i < 4; ++i)
#pragma unroll
        for (int j = 0; j < 4; ++j)
            acc[i][j] = (floatx4){0.f, 0.f, 0.f, 0.f};

    floatx4 accOnes[4];
    bf16x8 ones;
    if constexpr (MODE == 3) {
#pragma unroll
        for (int i = 0; i < 4; ++i) accOnes[i] = (floatx4){0.f, 0.f, 0.f, 0.f};
#pragma unroll
        for (int k = 0; k < 8; ++k) ones[k] = (__bf16)1.0f;
    }

    for (int kt = 0; kt < K; kt += 64) {
        __syncthreads();
#pragma unroll
        for (int it = 0; it < 4; ++it) {
            int ch = tid + it * 256;
            int r = ch >> 3;
            int c = (ch & 7) * 8;
            gload_lds16(A  + (long)(m0 + r) * lda + (kt + c), &As[ch * 8]);
            gload_lds16(Bt + (long)(n0 + r) * ldb + (kt + c), &Bs[ch * 8]);
        }
        __syncthreads();
#pragma unroll
        for (int kk = 0; kk < 64; kk += 32) {
            bf16x8 af[4], bfv[4];
#pragma unroll
            for (int i = 0; i < 4; ++i)
                af[i] = *(const bf16x8*)&As[(wy * 64 + i * 16 + lm) * 64 + kk + kq];
#pragma unroll
            for (int j = 0; j < 4; ++j)
                bfv[j] = *(const bf16x8*)&Bs[(wx * 64 + j * 16 + lm) * 64 + kk + kq];
#pragma unroll
            for (int i = 0; i < 4; ++i) {
#pragma unroll
                for (int j = 0; j < 4; ++j)
                    acc[i][j] = __builtin_amdgcn_mfma_f32_16x16x32_bf16(
                        af[i], bfv[j], acc[i][j], 0, 0, 0);
                if constexpr (MODE == 3)
                    accOnes[i] = __builtin_amdgcn_mfma_f32_16x16x32_bf16(
                        af[i], ones, accOnes[i], 0, 0, 0);
            }
        }
    }

    const int cr = (lane >> 4) * 4;
    if constexpr (MODE == 1) {
#pragma unroll
        for (int j = 0; j < 4; ++j) {
            int col = n0 + wx * 64 + j * 16 + lm;
#pragma unroll
            for (int i = 0; i < 4; ++i)
#pragma unroll
                for (int r = 0; r < 4; ++r) {
                    int row = m0 + wy * 64 + i * 16 + cr + r;
                    C[(long)row * ldc + col] = __float2bfloat16(__expf(acc[i][j][r]));
                }
        }
    } else if constexpr (MODE == 3) {
        floatx4 inv[4];
#pragma unroll
        for (int i = 0; i < 4; ++i)
#pragma unroll
            for (int r = 0; r < 4; ++r)
                inv[i][r] = 1.0f / accOnes[i][r];
#pragma unroll
        for (int j = 0; j < 4; ++j) {
            int col = n0 + wx * 64 + j * 16 + lm;
#pragma unroll
            for (int i = 0; i < 4; ++i)
#pragma unroll
                for (int r = 0; r < 4; ++r) {
                    int row = m0 + wy * 64 + i * 16 + cr + r;
                    C[(long)row * ldc + col] =
                        __float2bfloat16(acc[i][j][r] * inv[i][r]);
                }
        }
    } else {
#pragma unroll
        for (int j = 0; j < 4; ++j) {
            int col = n0 + wx * 64 + j * 16 + lm;
            float bv = (MODE == 0 && bias) ? __bfloat162float(bias[col]) : 0.f;
            float sc = (col < qcols) ? scale : 1.0f;
#pragma unroll
            for (int i = 0; i < 4; ++i) {
#pragma unroll
                for (int r = 0; r < 4; ++r) {
                    int row = m0 + wy * 64 + i * 16 + cr + r;
                    long idx = (long)row * ldc + col;
                    float v;
                    if (MODE == 2) v = acc[i][j][r] + __bfloat162float(C[idx]);
                    else           v = (acc[i][j][r] + bv) * sc;
                    C[idx] = __float2bfloat16(v);
                }
            }
        }
    }
}

// ---------- split-K GEMM, bf16 partials ---------------------------------
__global__ __launch_bounds__(256) void gemm_bt_splitk(
    const bf16* __restrict__ A, const bf16* __restrict__ Bt,
    bf16* __restrict__ P, int lda, int ldb, int ldp,
    long az, long bz, long pz, long skStride, int nsk, int Kc)
{
    __shared__ bf16 As[128 * 64];
    __shared__ bf16 Bs[128 * 64];

    const int tid  = threadIdx.x;
    const int lane = tid & 63;
    const int wave = tid >> 6;
    const int wx = wave & 1;
    const int wy = wave >> 1;
    const int zz = blockIdx.z;
    const int ks = zz % nsk;
    const int zh = zz / nsk;
    A  += (long)zh * az;
    Bt += (long)zh * bz;
    bf16* Pz = P + (long)zh * pz + (long)ks * skStride;
    const int m0 = blockIdx.y * 128;
    const int n0 = blockIdx.x * 128;
    const int k0 = ks * Kc;

    const int lm = lane & 15;
    const int kq = (lane >> 4) * 8;

    floatx4 acc[4][4];
#pragma unroll
    for (int i = 0; i < 4; ++i)
#pragma unroll
        for (int j = 0; j < 4; ++j)
            acc[i][j] = (floatx4){0.f, 0.f, 0.f, 0.f};

    for (int kt = k0; kt < k0 + Kc; kt += 64) {
        __syncthreads();
#pragma unroll
        for (int it = 0; it < 4; ++it) {
            int ch = tid + it * 256;
            int r = ch >> 3;
            int c = (ch & 7) * 8;
            gload_lds16(A  + (long)(m0 + r) * lda + (kt + c), &As[ch * 8]);
            gload_lds16(Bt + (long)(n0 + r) * ldb + (kt + c), &Bs[ch * 8]);
        }
        __syncthreads();
#pragma unroll
        for (int kk = 0; kk < 64; kk += 32) {
            bf16x8 af[4], bfv[4];
#pragma unroll
            for (int i = 0; i < 4; ++i)
                af[i] = *(const bf16x8*)&As[(wy * 64 + i * 16 + lm) * 64 + kk + kq];
#pragma unroll
            for (int j = 0; j < 4; ++j)
                bfv[j] = *(const bf16x8*)&Bs[(wx * 64 + j * 16 + lm) * 64 + kk + kq];
#pragma unroll
            for (int i = 0; i < 4; ++i)
#pragma unroll
                for (int j = 0; j < 4; ++j)
                    acc[i][j] = __builtin_amdgcn_mfma_f32_16x16x32_bf16(
                        af[i], bfv[j], acc[i][j], 0, 0, 0);
        }
    }

    const int cr = (lane >> 4) * 4;
#pragma unroll
    for (int j = 0; j < 4; ++j) {
        int col = n0 + wx * 64 + j * 16 + lm;
#pragma unroll
        for (int i = 0; i < 4; ++i)
#pragma unroll
            for (int r = 0; r < 4; ++r) {
                int row = m0 + wy * 64 + i * 16 + cr + r;
                Pz[(long)row * ldp + col] = __float2bfloat16(acc[i][j][r]);
            }
    }
}

// ---------- reduce bf16 split-K partials + bias -> bf16 (8-wide) ----------
__global__ __launch_bounds__(256) void reduce_splitk(
    const bf16* __restrict__ P, const bf16* __restrict__ bias,
    bf16* __restrict__ Out, long MN, int N, int SK)
{
    long i = ((long)blockIdx.x * 256 + threadIdx.x) * 8;
    if (i >= MN) return;
    float s[8];
    if (bias) {
        bf16 bb[8];
        *(float4*)bb = *(const float4*)&bias[i & (N - 1)];
#pragma unroll
        for (int k = 0; k < 8; ++k) s[k] = __bfloat162float(bb[k]);
    } else {
#pragma unroll
        for (int k = 0; k < 8; ++k) s[k] = 0.f;
    }
    for (int z = 0; z < SK; ++z) {
        bf16 a[8];
        *(float4*)a = *(const float4*)&P[(long)z * MN + i];
#pragma unroll
        for (int k = 0; k < 8; ++k) s[k] += __bfloat162float(a[k]);
    }
    bf16 o[8];
#pragma unroll
    for (int k = 0; k < 8; ++k) o[k] = __float2bfloat16(s[k]);
    *(float4*)&Out[i] = *(float4*)o;
}

// ---------- in-place softmax over rows of 2048 bf16 (fallback tiers) -----
__global__ __launch_bounds__(256) void softmax_rows2048(bf16* __restrict__ S)
{
    __shared__ float red[8];
    const long row = blockIdx.x;
    bf16* p = S + row * 2048;
    const int tid = threadIdx.x;
    float4 raw = *(const float4*)&p[tid * 8];
    bf16 vb[8];
    *(float4*)vb = raw;
    float v[8];
#pragma unroll
    for (int i = 0; i < 8; ++i) v[i] = __bfloat162float(vb[i]);
    float m = v[0];
#pragma unroll
    for (int i = 1; i < 8; ++i) m = fmaxf(m, v[i]);
#pragma unroll
    for (int o = 32; o > 0; o >>= 1) m = fmaxf(m, __shfl_xor(m, o));
    if ((tid & 63) == 0) red[tid >> 6] = m;
    __syncthreads();
    m = fmaxf(fmaxf(red[0], red[1]), fmaxf(red[2], red[3]));
    float s = 0.f;
#pragma unroll
    for (int i = 0; i < 8; ++i) { v[i] = __expf(v[i] - m); s += v[i]; }
#pragma unroll
    for (int o = 32; o > 0; o >>= 1) s += __shfl_xor(s, o);
    if ((tid & 63) == 0) red[4 + (tid >> 6)] = s;
    __syncthreads();
    s = (red[4] + red[5]) + (red[6] + red[7]);
    float inv = 1.f / s;
#pragma unroll
    for (int i = 0; i < 8; ++i) vb[i] = __float2bfloat16(v[i] * inv);
    *(float4*)&p[tid * 8] = *(float4*)vb;
}

extern "C" void kernel_launch(void* const* d_in, const int* in_sizes, int n_in,
                              void* d_out, int out_size, void* d_ws, size_t ws_size,
                              hipStream_t stream)
{
    const int Bb = 4, T = 2048, E = 512, H = 8;
    const int HE = H * E;            // 4096
    const int N3 = 3 * HE;           // 12288
    const int M  = Bb * T;           // 8192
    const long NX = (long)M * E;     // 4,194,304

    // ---- size-signature input assignment (order-robust) ----
    const void* xr = nullptr;
    const void* Wr[4] = {nullptr, nullptr, nullptr, nullptr};
    const void* br[3] = {nullptr, nullptr, nullptr};
    const void* bor = nullptr;
    int nw = 0, nb = 0;
    for (int i = 0; i < n_in; ++i) {
        int s = in_sizes[i];
        if      (s == (int)NX)      xr = d_in[i];
        else if (s == E * HE)       { if (nw < 4) Wr[nw++] = d_in[i]; }
        else if (s == HE)           { if (nb < 3) br[nb++] = d_in[i]; }
        else if (s == E)            bor = d_in[i];
    }
    if (!xr || nw < 4 || nb < 3 || !bor) {
        xr = d_in[0]; Wr[0] = d_in[1]; br[0] = d_in[2]; Wr[1] = d_in[3];
        br[1] = d_in[4]; Wr[2] = d_in[5]; br[2] = d_in[6]; Wr[3] = d_in[7];
        bor = d_in[8];
    }

    const float qscale = 0.04419417382415922f;  // 1/sqrt(512)
    const int   QC = 1 << 30;
    dim3 blk(256);

    // ---- workspace layout (bf16 elements) ----
    bf16* pool = (bf16*)d_ws;
    int*  flag = (int*)(void*)pool;
    bf16* xc   = pool + 8;
    bf16* bqc  = xc  + NX;     // bq|bk|bv contiguous (stacked bias [12288])
    bf16* bkc  = bqc + HE;
    bf16* bvc  = bkc + HE;
    bf16* boc  = bvc + HE;
    bf16* WqT  = boc + E;      // WqT|WkT|WvT contiguous (stacked Bt [12288,512])
    const size_t w2m = (size_t)E * HE;
    bf16* WkT  = WqT + w2m;
    bf16* WvT  = WkT + w2m;
    bf16* WoT  = WvT + w2m;
    bf16* Ofin = WoT + w2m;
    bf16* p0   = Ofin + NX;    // tier region

    const size_t wsE    = ws_size / sizeof(bf16);
    const size_t fixedE = (size_t)(p0 - pool);
    const size_t wQKV  = (size_t)T * N3;      // 25.17M el
    const size_t wBat  = (size_t)T * HE;      // 8.39M el
    const size_t wHd   = (size_t)T * E;       // 1.05M el
    const size_t sAll  = (size_t)H * T * T;   // 33.55M el
    const size_t sOne  = (size_t)T * T;
    const size_t wBig  = (size_t)M * HE;      // 33.55M el
    const size_t needB2 = fixedE + wQKV + wBat + sAll + wBig;  // ~235 MB
    const size_t needB  = fixedE + wQKV + 2 * wBat + sAll;     // ~185 MB
    const size_t needC  = fixedE + 5 * wBat + sOne;
    const size_t needD  = fixedE + 5 * wHd  + sOne;
    if (wsE < needD) return;

    // ---- stage 0: dtype probe + canonicalize ----
    probe_dtype<<<dim3(1), blk, 0, stream>>>((const float*)xr, flag);
    convert_to_bf16<<<dim3((unsigned)((NX / 8 + 255) / 256)), blk, 0, stream>>>(
        xr, xc, NX, flag);
    convert_to_bf16<<<dim3(2), blk, 0, stream>>>(br[0], bqc, HE, flag);
    convert_to_bf16<<<dim3(2), blk, 0, stream>>>(br[1], bkc, HE, flag);
    convert_to_bf16<<<dim3(2), blk, 0, stream>>>(br[2], bvc, HE, flag);
    convert_to_bf16<<<dim3(1), blk, 0, stream>>>(bor, boc, E, flag);
    transpose_any<<<dim3(HE / 64, E / 64, 1), blk, 0, stream>>>(Wr[0], WqT, HE, E, flag);
    transpose_any<<<dim3(HE / 64, E / 64, 1), blk, 0, stream>>>(Wr[1], WkT, HE, E, flag);
    transpose_any<<<dim3(HE / 64, E / 64, 1), blk, 0, stream>>>(Wr[2], WvT, HE, E, flag);
    transpose_any<<<dim3(E / 64, HE / 64, 1), blk, 0, stream>>>(Wr[3], WoT, E, HE, flag);

    if (wsE >= needB2) {
        // ---- Tier B2: exp-in-QK + L-via-ones-MFMA in PV (no softmax pass,
        //      no reduce_pv, no atomics) ----
        bf16* QKVb = p0;                 // [t, 12288]; aliased for out-proj P
        bf16* Vtb  = QKVb + wQKV;        // [h,e,t]
        bf16* S    = Vtb + wBat;         // exp(scores) [h,t,s]
        bf16* Oatt = S + sAll;           // O_all [M, HE]

        for (int b = 0; b < Bb; ++b) {
            const bf16* xb = xc + (size_t)b * T * E;
            // merged QKV projection (qscale on Q cols only)
            gemm_bt<0><<<dim3(N3 / 128, T / 128, 1), blk, 0, stream>>>(
                xb, WqT, QKVb, bqc, E, E, N3, 0, 0, 0, E, qscale, HE);
            transpose_bf16<<<dim3(E / 64, T / 64, H), blk, 0, stream>>>(
                QKVb + 2 * HE, Vtb, N3, T, H, (long)E, (long)E * T, 0, 0);
            // QK: S = exp(Q K^T)
            gemm_bt<1><<<dim3(T / 128, T / 128, H), blk, 0, stream>>>(
                QKVb, QKVb + HE, S, nullptr, N3, N3, T,
                (long)E, (long)E, (long)T * T, E, 1.f, QC);
            // PV: O = (S V) / rowsum(S); rowsum via ones-MFMA (K spans full row)
            gemm_bt<3><<<dim3(E / 128, T / 128, H), blk, 0, stream>>>(
                S, Vtb, Oatt + (size_t)b * T * HE, nullptr, T, T, HE,
                (long)T * T, (long)E * T, (long)E, T, 1.f, QC);
        }
        // out-proj: split-K=2, bf16 partials alias QKVb (dead)
        gemm_bt_splitk<<<dim3(E / 128, M / 128, 2), blk, 0, stream>>>(
            Oatt, WoT, QKVb, HE, HE, E, 0, 0, 0, (long)M * E, 2, HE / 2);
        reduce_splitk<<<dim3((unsigned)((NX / 8 + 255) / 256)), blk, 0, stream>>>(
            QKVb, boc, Ofin, NX, E, 2);
    } else if (wsE >= needB) {
        // ---- Tier B fallback: softmax path ----
        bf16* QKVb = p0;
        bf16* Vtb  = QKVb + wQKV;
        bf16* Oatt = Vtb + wBat;
        bf16* S    = Oatt + wBat;

        for (int b = 0; b < Bb; ++b) {
            const bf16* xb = xc + (size_t)b * T * E;
            gemm_bt<0><<<dim3(N3 / 128, T / 128, 1), blk, 0, stream>>>(
                xb, WqT, QKVb, bqc, E, E, N3, 0, 0, 0, E, qscale, HE);
            transpose_bf16<<<dim3(E / 64, T / 64, H), blk, 0, stream>>>(
                QKVb + 2 * HE, Vtb, N3, T, H, (long)E, (long)E * T, 0, 0);
            gemm_bt<0><<<dim3(T / 128, T / 128, H), blk, 0, stream>>>(
                QKVb, QKVb + HE, S, nullptr, N3, N3, T,
                (long)E, (long)E, (long)T * T, E, 1.f, QC);
            softmax_rows2048<<<dim3(H * T, 1, 1), blk, 0, stream>>>(S);
            gemm_bt<0><<<dim3(E / 128, T / 128, H), blk, 0, stream>>>(
                S, Vtb, Oatt, nullptr, T, T, HE,
                (long)T * T, (long)E * T, (long)E, T, 1.f, QC);
            gemm_bt_splitk<<<dim3(E / 128, T / 128, 8), blk, 0, stream>>>(
                Oatt, WoT, (bf16*)S, HE, HE, E, 0, 0, 0, (long)T * E, 8, HE / 8);
            reduce_splitk<<<dim3((unsigned)(((long)T * E / 8 + 255) / 256)), blk, 0, stream>>>(
                (bf16*)S, boc, Ofin + (size_t)b * T * E, (long)T * E, E, 8);
        }
    } else if (wsE >= needC) {
        // ---- Tier C fallback ----
        bf16* Qb  = p0;
        bf16* Kb  = Qb  + wBat;
        bf16* Vb  = Kb  + wBat;
        bf16* Vtb = Vb  + wBat;
        bf16* Ob  = Vtb + wBat;
        bf16* S   = Ob  + wBat;

        for (int b = 0; b < Bb; ++b) {
            const bf16* xb = xc + (size_t)b * T * E;
            gemm_bt<0><<<dim3(HE / 128, T / 128, 1), blk, 0, stream>>>(
                xb, WqT, Qb, bqc, E, E, HE, 0, 0, 0, E, qscale, QC);
            gemm_bt<0><<<dim3(HE / 128, T / 128, 1), blk, 0, stream>>>(
                xb, WkT, Kb, bkc, E, E, HE, 0, 0, 0, E, 1.f, QC);
            gemm_bt<0><<<dim3(HE / 128, T / 128, 1), blk, 0, stream>>>(
                xb, WvT, Vb, bvc, E, E, HE, 0, 0, 0, E, 1.f, QC);
            transpose_bf16<<<dim3(E / 64, T / 64, H), blk, 0, stream>>>(
                Vb, Vtb, HE, T, H, (long)E, (long)E * T, 0, 0);
            for (int h = 0; h < H; ++h) {
                gemm_bt<0><<<dim3(T / 128, T / 128, 1), blk, 0, stream>>>(
                    Qb + (size_t)h * E, Kb + (size_t)h * E, S, nullptr,
                    HE, HE, T, 0, 0, 0, E, 1.f, QC);
                softmax_rows2048<<<dim3(T, 1, 1), blk, 0, stream>>>(S);
                gemm_bt<0><<<dim3(E / 128, T / 128, 1), blk, 0, stream>>>(
                    S, Vtb + (size_t)h * E * T, Ob + (size_t)h * E, nullptr,
                    T, T, HE, 0, 0, 0, T, 1.f, QC);
            }
            gemm_bt<0><<<dim3(E / 128, T / 128, 1), blk, 0, stream>>>(
                Ob, WoT, Ofin + (size_t)b * T * E, boc,
                HE, HE, E, 0, 0, 0, HE, 1.f, QC);
        }
    } else {
        // ---- Tier D fallback ----
        bf16* Qh  = p0;
        bf16* Kh  = Qh  + wHd;
        bf16* Vh  = Kh  + wHd;
        bf16* Vth = Vh  + wHd;
        bf16* Oh  = Vth + wHd;
        bf16* S   = Oh  + wHd;

        for (int b = 0; b < Bb; ++b) {
            const bf16* xb = xc + (size_t)b * T * E;
            bf16* outb = Ofin + (size_t)b * T * E;
            for (int h = 0; h < H; ++h) {
                const size_t hw = (size_t)h * E * E;
                gemm_bt<0><<<dim3(E / 128, T / 128, 1), blk, 0, stream>>>(
                    xb, WqT + hw, Qh, bqc + (size_t)h * E, E, E, E,
                    0, 0, 0, E, qscale, QC);
                gemm_bt<0><<<dim3(E / 128, T / 128, 1), blk, 0, stream>>>(
                    xb, WkT + hw, Kh, bkc + (size_t)h * E, E, E, E,
                    0, 0, 0, E, 1.f, QC);
                gemm_bt<0><<<dim3(E / 128, T / 128, 1), blk, 0, stream>>>(
                    xb, WvT + hw, Vh, bvc + (size_t)h * E, E, E, E,
                    0, 0, 0, E, 1.f, QC);
                transpose_bf16<<<dim3(E / 64, T / 64, 1), blk, 0, stream>>>(
                    Vh, Vth, E, T, 1, 0, 0, 0, 0);
                gemm_bt<0><<<dim3(T / 128, T / 128, 1), blk, 0, stream>>>(
                    Qh, Kh, S, nullptr, E, E, T, 0, 0, 0, E, 1.f, QC);
                softmax_rows2048<<<dim3(T, 1, 1), blk, 0, stream>>>(S);
                gemm_bt<0><<<dim3(E / 128, T / 128, 1), blk, 0, stream>>>(
                    S, Vth, Oh, nullptr, T, T, E, 0, 0, 0, T, 1.f, QC);
                if (h == 0)
                    gemm_bt<0><<<dim3(E / 128, T / 128, 1), blk, 0, stream>>>(
                        Oh, WoT, outb, boc, E, HE, E, 0, 0, 0, E, 1.f, QC);
                else
                    gemm_bt<2><<<dim3(E / 128, T / 128, 1), blk, 0, stream>>>(
                        Oh, WoT + (size_t)h * E, outb, nullptr,
                        E, HE, E, 0, 0, 0, E, 1.f, QC);
            }
        }
    }

    // ---- emit in the probed dtype ----
    emit_out<<<dim3((unsigned)((NX / 8 + 255) / 256)), blk, 0, stream>>>(
        Ofin, d_out, NX, flag);
}

// Round 9
// 950.183 us; speedup vs baseline: 1.2132x; 1.0469x over previous
//
#include <hip/hip_runtime.h>
#include <hip/hip_bf16.h>
#include <stdint.h>

typedef __hip_bfloat16 bf16;
typedef __bf16 bf16x8 __attribute__((ext_vector_type(8)));
typedef float floatx4 __attribute__((ext_vector_type(4)));

#define AS_LDS __attribute__((address_space(3)))
#define AS_GLB __attribute__((address_space(1)))

__device__ __forceinline__ void gload_lds16(const bf16* g, bf16* l) {
    __builtin_amdgcn_global_load_lds((const AS_GLB void*)g, (AS_LDS void*)l, 16, 0, 0);
}

// ---------- dtype probe: *flag = 1 if x is fp32, 0 if bf16 ----------
__global__ void probe_dtype(const float* __restrict__ x, int* __restrict__ flag) {
    __shared__ int cnt;
    if (threadIdx.x == 0) cnt = 0;
    __syncthreads();
    int ok = 0;
    for (int i = threadIdx.x; i < 4096; i += 256) {
        float v = x[i];
        if (v == v && fabsf(v) < 1.0e3f) ok++;
    }
    atomicAdd(&cnt, ok);
    __syncthreads();
    if (threadIdx.x == 0) *flag = (cnt > 2048) ? 1 : 0;
}

// ---------- convert raw (fp32 or bf16 per flag) -> canonical bf16 ----------
__global__ __launch_bounds__(256) void convert_to_bf16(
    const void* __restrict__ in, bf16* __restrict__ out, long n,
    const int* __restrict__ flag)
{
    long i = ((long)blockIdx.x * 256 + threadIdx.x) * 8;
    if (i >= n) return;
    bf16 o[8];
    if (*flag) {
        const float* p = (const float*)in + i;
        float4 a = *(const float4*)p;
        float4 b = *(const float4*)(p + 4);
        o[0] = __float2bfloat16(a.x); o[1] = __float2bfloat16(a.y);
        o[2] = __float2bfloat16(a.z); o[3] = __float2bfloat16(a.w);
        o[4] = __float2bfloat16(b.x); o[5] = __float2bfloat16(b.y);
        o[6] = __float2bfloat16(b.z); o[7] = __float2bfloat16(b.w);
    } else {
        *(float4*)o = *(const float4*)((const bf16*)in + i);
    }
    *(float4*)&out[i] = *(float4*)o;
}

// ---------- emit canonical bf16 -> d_out in flag dtype (fallback tiers) ----
__global__ __launch_bounds__(256) void emit_out(
    const bf16* __restrict__ in, void* __restrict__ out, long n,
    const int* __restrict__ flag)
{
    long i = ((long)blockIdx.x * 256 + threadIdx.x) * 8;
    if (i >= n) return;
    bf16 v[8];
    *(float4*)v = *(const float4*)&in[i];
    if (*flag) {
        float* o = (float*)out + i;
        float4 a, b;
        a.x = __bfloat162float(v[0]); a.y = __bfloat162float(v[1]);
        a.z = __bfloat162float(v[2]); a.w = __bfloat162float(v[3]);
        b.x = __bfloat162float(v[4]); b.y = __bfloat162float(v[5]);
        b.z = __bfloat162float(v[6]); b.w = __bfloat162float(v[7]);
        *(float4*)o = a;
        *(float4*)(o + 4) = b;
    } else {
        *(float4*)((bf16*)out + i) = *(float4*)v;
    }
}

// ---------- transpose raw-dtype input -> bf16 output ----------
__global__ __launch_bounds__(256) void transpose_any(
    const void* __restrict__ inv, bf16* __restrict__ out,
    int ldin, int ldout, const int* __restrict__ flag)
{
    __shared__ bf16 tile[64][80];
    const int fp32 = *flag;
    const int c0 = blockIdx.x * 64;
    const int r0 = blockIdx.y * 64;
    const int tid = threadIdx.x;
#pragma unroll
    for (int it = 0; it < 2; ++it) {
        int ch = tid + it * 256;
        int r = ch >> 3, c = (ch & 7) * 8;
        long eidx = (long)(r0 + r) * ldin + (c0 + c);
        if (fp32) {
            const float* p = (const float*)inv + eidx;
            float4 a = *(const float4*)p;
            float4 b = *(const float4*)(p + 4);
            bf16 o[8];
            o[0] = __float2bfloat16(a.x); o[1] = __float2bfloat16(a.y);
            o[2] = __float2bfloat16(a.z); o[3] = __float2bfloat16(a.w);
            o[4] = __float2bfloat16(b.x); o[5] = __float2bfloat16(b.y);
            o[6] = __float2bfloat16(b.z); o[7] = __float2bfloat16(b.w);
            *(float4*)&tile[r][c] = *(float4*)o;
        } else {
            *(float4*)&tile[r][c] = *(const float4*)((const bf16*)inv + eidx);
        }
    }
    __syncthreads();
#pragma unroll
    for (int it = 0; it < 2; ++it) {
        int ch = tid + it * 256;
        int oc = ch >> 3, rb = (ch & 7) * 8;
        bf16 tmp[8];
#pragma unroll
        for (int i = 0; i < 8; ++i) tmp[i] = tile[rb + i][oc];
        *(float4*)&out[(long)(c0 + oc) * ldout + r0 + rb] = *(float4*)tmp;
    }
}

// ---------- pure-bf16 transpose (fallback tiers) ----------
__global__ __launch_bounds__(256) void transpose_bf16(
    const bf16* __restrict__ in, bf16* __restrict__ out,
    int ldin, int ldout,
    int nz1, long in_z1, long out_z1, long in_z2, long out_z2)
{
    __shared__ bf16 tile[64][80];
    const int z = blockIdx.z;
    const int z1 = z % nz1, z2 = z / nz1;
    in  += (long)z1 * in_z1 + (long)z2 * in_z2;
    out += (long)z1 * out_z1 + (long)z2 * out_z2;
    const int c0 = blockIdx.x * 64;
    const int r0 = blockIdx.y * 64;
    const int tid = threadIdx.x;
#pragma unroll
    for (int it = 0; it < 2; ++it) {
        int ch = tid + it * 256;
        int r = ch >> 3, c = (ch & 7) * 8;
        *(float4*)&tile[r][c] = *(const float4*)&in[(long)(r0 + r) * ldin + c0 + c];
    }
    __syncthreads();
#pragma unroll
    for (int it = 0; it < 2; ++it) {
        int ch = tid + it * 256;
        int oc = ch >> 3, rb = (ch & 7) * 8;
        bf16 tmp[8];
#pragma unroll
        for (int i = 0; i < 8; ++i) tmp[i] = tile[rb + i][oc];
        *(float4*)&out[(long)(c0 + oc) * ldout + r0 + rb] = *(float4*)tmp;
    }
}

// ---------- GEMM (bf16 in/out, fp32 acc), templated epilogue -------------
// MODE 0: C = (acc + bias) * (col<qcols ? scale : 1)
// MODE 1: C = exp(acc)
// MODE 2: C += acc   (tier-D accumulate)
// MODE 3: C = acc / L, L = row-sum of A via ones-MFMA (K spans full row)
// MODE 4: QKV projection with fused V-transpose: cols < vcol0 behave like
//         MODE 0 into C; cols >= vcol0 are V: written transposed into
//         Vt[h= (col-vcol0)>>9][e=(col-vcol0)&511][t=row] as packed 8B
//         stores (the 4 acc regs are 4 consecutive t). Branch is
//         block-uniform (n0 128-aligned, vcol0 multiple of 128).
template <int MODE>
__global__ __launch_bounds__(256) void gemm_bt(
    const bf16* __restrict__ A, const bf16* __restrict__ Bt,
    bf16* __restrict__ C, const bf16* __restrict__ bias,
    int lda, int ldb, int ldc,
    long az, long bz, long cz, int K, float scale, int qcols,
    bf16* __restrict__ Vt, int vcol0)
{
    __shared__ bf16 As[128 * 64];
    __shared__ bf16 Bs[128 * 64];

    const int tid  = threadIdx.x;
    const int lane = tid & 63;
    const int wave = tid >> 6;
    const int wx = wave & 1;
    const int wy = wave >> 1;
    const long zz = blockIdx.z;
    A  += zz * az;
    Bt += zz * bz;
    C  += zz * cz;
    const int m0 = blockIdx.y * 128;
    const int n0 = blockIdx.x * 128;

    const int lm = lane & 15;
    const int kq = (lane >> 4) * 8;

    floatx4 acc[4][4];
#pragma unroll
    for (int i = 0; i < 4; ++i)
#pragma unroll
        for (int j = 0; j < 4; ++j)
            acc[i][j] = (floatx4){0.f, 0.f, 0.f, 0.f};

    floatx4 accOnes[4];
    bf16x8 ones;
    if constexpr (MODE == 3) {
#pragma unroll
        for (int i = 0; i < 4; ++i) accOnes[i] = (floatx4){0.f, 0.f, 0.f, 0.f};
#pragma unroll
        for (int k = 0; k < 8; ++k) ones[k] = (__bf16)1.0f;
    }

    for (int kt = 0; kt < K; kt += 64) {
        __syncthreads();
#pragma unroll
        for (int it = 0; it < 4; ++it) {
            int ch = tid + it * 256;
            int r = ch >> 3;
            int c = (ch & 7) * 8;
            gload_lds16(A  + (long)(m0 + r) * lda + (kt + c), &As[ch * 8]);
            gload_lds16(Bt + (long)(n0 + r) * ldb + (kt + c), &Bs[ch * 8]);
        }
        __syncthreads();
#pragma unroll
        for (int kk = 0; kk < 64; kk += 32) {
            bf16x8 af[4], bfv[4];
#pragma unroll
            for (int i = 0; i < 4; ++i)
                af[i] = *(const bf16x8*)&As[(wy * 64 + i * 16 + lm) * 64 + kk + kq];
#pragma unroll
            for (int j = 0; j < 4; ++j)
                bfv[j] = *(const bf16x8*)&Bs[(wx * 64 + j * 16 + lm) * 64 + kk + kq];
#pragma unroll
            for (int i = 0; i < 4; ++i) {
#pragma unroll
                for (int j = 0; j < 4; ++j)
                    acc[i][j] = __builtin_amdgcn_mfma_f32_16x16x32_bf16(
                        af[i], bfv[j], acc[i][j], 0, 0, 0);
                if constexpr (MODE == 3)
                    accOnes[i] = __builtin_amdgcn_mfma_f32_16x16x32_bf16(
                        af[i], ones, accOnes[i], 0, 0, 0);
            }
        }
    }

    const int cr = (lane >> 4) * 4;
    if constexpr (MODE == 1) {
#pragma unroll
        for (int j = 0; j < 4; ++j) {
            int col = n0 + wx * 64 + j * 16 + lm;
#pragma unroll
            for (int i = 0; i < 4; ++i)
#pragma unroll
                for (int r = 0; r < 4; ++r) {
                    int row = m0 + wy * 64 + i * 16 + cr + r;
                    C[(long)row * ldc + col] = __float2bfloat16(__expf(acc[i][j][r]));
                }
        }
    } else if constexpr (MODE == 3) {
        floatx4 inv[4];
#pragma unroll
        for (int i = 0; i < 4; ++i)
#pragma unroll
            for (int r = 0; r < 4; ++r)
                inv[i][r] = 1.0f / accOnes[i][r];
#pragma unroll
        for (int j = 0; j < 4; ++j) {
            int col = n0 + wx * 64 + j * 16 + lm;
#pragma unroll
            for (int i = 0; i < 4; ++i)
#pragma unroll
                for (int r = 0; r < 4; ++r) {
                    int row = m0 + wy * 64 + i * 16 + cr + r;
                    C[(long)row * ldc + col] =
                        __float2bfloat16(acc[i][j][r] * inv[i][r]);
                }
        }
    } else if constexpr (MODE == 4) {
        if (n0 >= vcol0) {
            // V block: write transposed, packed 4 consecutive t per 8B store
#pragma unroll
            for (int j = 0; j < 4; ++j) {
                int col = n0 + wx * 64 + j * 16 + lm;
                float bv = __bfloat162float(bias[col]);
                int eg = col - vcol0;
                bf16* vt = Vt + ((long)(eg >> 9) * 512 + (eg & 511)) * 2048;
#pragma unroll
                for (int i = 0; i < 4; ++i) {
                    int t0 = m0 + wy * 64 + i * 16 + cr;
                    bf16 pk[4];
#pragma unroll
                    for (int r = 0; r < 4; ++r)
                        pk[r] = __float2bfloat16(acc[i][j][r] + bv);
                    *(ushort4*)&vt[t0] = *(ushort4*)pk;
                }
            }
        } else {
#pragma unroll
            for (int j = 0; j < 4; ++j) {
                int col = n0 + wx * 64 + j * 16 + lm;
                float bv = __bfloat162float(bias[col]);
                float sc = (col < qcols) ? scale : 1.0f;
#pragma unroll
                for (int i = 0; i < 4; ++i)
#pragma unroll
                    for (int r = 0; r < 4; ++r) {
                        int row = m0 + wy * 64 + i * 16 + cr + r;
                        C[(long)row * ldc + col] =
                            __float2bfloat16((acc[i][j][r] + bv) * sc);
                    }
            }
        }
    } else {
#pragma unroll
        for (int j = 0; j < 4; ++j) {
            int col = n0 + wx * 64 + j * 16 + lm;
            float bv = (MODE == 0 && bias) ? __bfloat162float(bias[col]) : 0.f;
            float sc = (col < qcols) ? scale : 1.0f;
#pragma unroll
            for (int i = 0; i < 4; ++i) {
#pragma unroll
                for (int r = 0; r < 4; ++r) {
                    int row = m0 + wy * 64 + i * 16 + cr + r;
                    long idx = (long)row * ldc + col;
                    float v;
                    if (MODE == 2) v = acc[i][j][r] + __bfloat162float(C[idx]);
                    else           v = (acc[i][j][r] + bv) * sc;
                    C[idx] = __float2bfloat16(v);
                }
            }
        }
    }
}

// ---------- split-K GEMM, bf16 partials ---------------------------------
__global__ __launch_bounds__(256) void gemm_bt_splitk(
    const bf16* __restrict__ A, const bf16* __restrict__ Bt,
    bf16* __restrict__ P, int lda, int ldb, int ldp,
    long az, long bz, long pz, long skStride, int nsk, int Kc)
{
    __shared__ bf16 As[128 * 64];
    __shared__ bf16 Bs[128 * 64];

    const int tid  = threadIdx.x;
    const int lane = tid & 63;
    const int wave = tid >> 6;
    const int wx = wave & 1;
    const int wy = wave >> 1;
    const int zz = blockIdx.z;
    const int ks = zz % nsk;
    const int zh = zz / nsk;
    A  += (long)zh * az;
    Bt += (long)zh * bz;
    bf16* Pz = P + (long)zh * pz + (long)ks * skStride;
    const int m0 = blockIdx.y * 128;
    const int n0 = blockIdx.x * 128;
    const int k0 = ks * Kc;

    const int lm = lane & 15;
    const int kq = (lane >> 4) * 8;

    floatx4 acc[4][4];
#pragma unroll
    for (int i = 0; i < 4; ++i)
#pragma unroll
        for (int j = 0; j < 4; ++j)
            acc[i][j] = (floatx4){0.f, 0.f, 0.f, 0.f};

    for (int kt = k0; kt < k0 + Kc; kt += 64) {
        __syncthreads();
#pragma unroll
        for (int it = 0; it < 4; ++it) {
            int ch = tid + it * 256;
            int r = ch >> 3;
            int c = (ch & 7) * 8;
            gload_lds16(A  + (long)(m0 + r) * lda + (kt + c), &As[ch * 8]);
            gload_lds16(Bt + (long)(n0 + r) * ldb + (kt + c), &Bs[ch * 8]);
        }
        __syncthreads();
#pragma unroll
        for (int kk = 0; kk < 64; kk += 32) {
            bf16x8 af[4], bfv[4];
#pragma unroll
            for (int i = 0; i < 4; ++i)
                af[i] = *(const bf16x8*)&As[(wy * 64 + i * 16 + lm) * 64 + kk + kq];
#pragma unroll
            for (int j = 0; j < 4; ++j)
                bfv[j] = *(const bf16x8*)&Bs[(wx * 64 + j * 16 + lm) * 64 + kk + kq];
#pragma unroll
            for (int i = 0; i < 4; ++i)
#pragma unroll
                for (int j = 0; j < 4; ++j)
                    acc[i][j] = __builtin_amdgcn_mfma_f32_16x16x32_bf16(
                        af[i], bfv[j], acc[i][j], 0, 0, 0);
        }
    }

    const int cr = (lane >> 4) * 4;
#pragma unroll
    for (int j = 0; j < 4; ++j) {
        int col = n0 + wx * 64 + j * 16 + lm;
#pragma unroll
        for (int i = 0; i < 4; ++i)
#pragma unroll
            for (int r = 0; r < 4; ++r) {
                int row = m0 + wy * 64 + i * 16 + cr + r;
                Pz[(long)row * ldp + col] = __float2bfloat16(acc[i][j][r]);
            }
    }
}

// ---------- reduce 2 bf16 split-K partials + bias -> d_out in flag dtype ----
__global__ __launch_bounds__(256) void reduce_emit(
    const bf16* __restrict__ P, const bf16* __restrict__ bias,
    void* __restrict__ out, long MN, int N,
    const int* __restrict__ flag)
{
    long i = ((long)blockIdx.x * 256 + threadIdx.x) * 8;
    if (i >= MN) return;
    bf16 bb[8], a[8], b[8];
    *(float4*)bb = *(const float4*)&bias[i & (N - 1)];
    *(float4*)a  = *(const float4*)&P[i];
    *(float4*)b  = *(const float4*)&P[MN + i];
    float s[8];
#pragma unroll
    for (int k = 0; k < 8; ++k)
        s[k] = __bfloat162float(bb[k]) + __bfloat162float(a[k]) + __bfloat162float(b[k]);
    if (*flag) {
        float* o = (float*)out + i;
        float4 lo = {s[0], s[1], s[2], s[3]};
        float4 hi = {s[4], s[5], s[6], s[7]};
        *(float4*)o = lo;
        *(float4*)(o + 4) = hi;
    } else {
        bf16 o[8];
#pragma unroll
        for (int k = 0; k < 8; ++k) o[k] = __float2bfloat16(s[k]);
        *(float4*)&((bf16*)out)[i] = *(float4*)o;
    }
}

// ---------- reduce bf16 split-K partials + bias -> bf16 (fallback) ----------
__global__ __launch_bounds__(256) void reduce_splitk(
    const bf16* __restrict__ P, const bf16* __restrict__ bias,
    bf16* __restrict__ Out, long MN, int N, int SK)
{
    long i = ((long)blockIdx.x * 256 + threadIdx.x) * 8;
    if (i >= MN) return;
    float s[8];
    if (bias) {
        bf16 bb[8];
        *(float4*)bb = *(const float4*)&bias[i & (N - 1)];
#pragma unroll
        for (int k = 0; k < 8; ++k) s[k] = __bfloat162float(bb[k]);
    } else {
#pragma unroll
        for (int k = 0; k < 8; ++k) s[k] = 0.f;
    }
    for (int z = 0; z < SK; ++z) {
        bf16 a[8];
        *(float4*)a = *(const float4*)&P[(long)z * MN + i];
#pragma unroll
        for (int k = 0; k < 8; ++k) s[k] += __bfloat162float(a[k]);
    }
    bf16 o[8];
#pragma unroll
    for (int k = 0; k < 8; ++k) o[k] = __float2bfloat16(s[k]);
    *(float4*)&Out[i] = *(float4*)o;
}

// ---------- in-place softmax over rows of 2048 bf16 (fallback tiers) -----
__global__ __launch_bounds__(256) void softmax_rows2048(bf16* __restrict__ S)
{
    __shared__ float red[8];
    const long row = blockIdx.x;
    bf16* p = S + row * 2048;
    const int tid = threadIdx.x;
    float4 raw = *(const float4*)&p[tid * 8];
    bf16 vb[8];
    *(float4*)vb = raw;
    float v[8];
#pragma unroll
    for (int i = 0; i < 8; ++i) v[i] = __bfloat162float(vb[i]);
    float m = v[0];
#pragma unroll
    for (int i = 1; i < 8; ++i) m = fmaxf(m, v[i]);
#pragma unroll
    for (int o = 32; o > 0; o >>= 1) m = fmaxf(m, __shfl_xor(m, o));
    if ((tid & 63) == 0) red[tid >> 6] = m;
    __syncthreads();
    m = fmaxf(fmaxf(red[0], red[1]), fmaxf(red[2], red[3]));
    float s = 0.f;
#pragma unroll
    for (int i = 0; i < 8; ++i) { v[i] = __expf(v[i] - m); s += v[i]; }
#pragma unroll
    for (int o = 32; o > 0; o >>= 1) s += __shfl_xor(s, o);
    if ((tid & 63) == 0) red[4 + (tid >> 6)] = s;
    __syncthreads();
    s = (red[4] + red[5]) + (red[6] + red[7]);
    float inv = 1.f / s;
#pragma unroll
    for (int i = 0; i < 8; ++i) vb[i] = __float2bfloat16(v[i] * inv);
    *(float4*)&p[tid * 8] = *(float4*)vb;
}

extern "C" void kernel_launch(void* const* d_in, const int* in_sizes, int n_in,
                              void* d_out, int out_size, void* d_ws, size_t ws_size,
                              hipStream_t stream)
{
    const int Bb = 4, T = 2048, E = 512, H = 8;
    const int HE = H * E;            // 4096
    const int N3 = 3 * HE;           // 12288
    const int N2 = 2 * HE;           // 8192 (Q|K row width after V split-out)
    const int M  = Bb * T;           // 8192
    const long NX = (long)M * E;     // 4,194,304

    // ---- size-signature input assignment (order-robust) ----
    const void* xr = nullptr;
    const void* Wr[4] = {nullptr, nullptr, nullptr, nullptr};
    const void* br[3] = {nullptr, nullptr, nullptr};
    const void* bor = nullptr;
    int nw = 0, nb = 0;
    for (int i = 0; i < n_in; ++i) {
        int s = in_sizes[i];
        if      (s == (int)NX)      xr = d_in[i];
        else if (s == E * HE)       { if (nw < 4) Wr[nw++] = d_in[i]; }
        else if (s == HE)           { if (nb < 3) br[nb++] = d_in[i]; }
        else if (s == E)            bor = d_in[i];
    }
    if (!xr || nw < 4 || nb < 3 || !bor) {
        xr = d_in[0]; Wr[0] = d_in[1]; br[0] = d_in[2]; Wr[1] = d_in[3];
        br[1] = d_in[4]; Wr[2] = d_in[5]; br[2] = d_in[6]; Wr[3] = d_in[7];
        bor = d_in[8];
    }

    const float qscale = 0.04419417382415922f;  // 1/sqrt(512)
    const int   QC = 1 << 30;
    dim3 blk(256);

    // ---- workspace layout (bf16 elements) ----
    bf16* pool = (bf16*)d_ws;
    int*  flag = (int*)(void*)pool;
    bf16* xc   = pool + 8;
    bf16* bqc  = xc  + NX;     // bq|bk|bv contiguous (stacked bias [12288])
    bf16* bkc  = bqc + HE;
    bf16* bvc  = bkc + HE;
    bf16* boc  = bvc + HE;
    bf16* WqT  = boc + E;      // WqT|WkT|WvT contiguous (stacked Bt [12288,512])
    const size_t w2m = (size_t)E * HE;
    bf16* WkT  = WqT + w2m;
    bf16* WvT  = WkT + w2m;
    bf16* WoT  = WvT + w2m;
    bf16* Ofin = WoT + w2m;
    bf16* p0   = Ofin + NX;    // tier region

    const size_t wsE    = ws_size / sizeof(bf16);
    const size_t fixedE = (size_t)(p0 - pool);
    const size_t wQK   = (size_t)T * N2;      // 16.8M el — per-batch Q|K
    const size_t wQKV  = (size_t)T * N3;      // 25.17M el (tier-B fallback)
    const size_t wBat  = (size_t)T * HE;      // 8.39M el
    const size_t wHd   = (size_t)T * E;       // 1.05M el
    const size_t sAll  = (size_t)H * T * T;   // 33.55M el
    const size_t sOne  = (size_t)T * T;
    const size_t wBig  = (size_t)M * HE;      // 33.55M el
    const size_t needB2 = fixedE + wQK + wBat + sAll + wBig;   // ~218 MB
    const size_t needB  = fixedE + wQKV + 2 * wBat + sAll;     // ~185 MB
    const size_t needC  = fixedE + 5 * wBat + sOne;
    const size_t needD  = fixedE + 5 * wHd  + sOne;
    if (wsE < needD) return;

    // ---- stage 0: dtype probe + canonicalize ----
    probe_dtype<<<dim3(1), blk, 0, stream>>>((const float*)xr, flag);
    convert_to_bf16<<<dim3((unsigned)((NX / 8 + 255) / 256)), blk, 0, stream>>>(
        xr, xc, NX, flag);
    convert_to_bf16<<<dim3(2), blk, 0, stream>>>(br[0], bqc, HE, flag);
    convert_to_bf16<<<dim3(2), blk, 0, stream>>>(br[1], bkc, HE, flag);
    convert_to_bf16<<<dim3(2), blk, 0, stream>>>(br[2], bvc, HE, flag);
    convert_to_bf16<<<dim3(1), blk, 0, stream>>>(bor, boc, E, flag);
    transpose_any<<<dim3(HE / 64, E / 64, 1), blk, 0, stream>>>(Wr[0], WqT, HE, E, flag);
    transpose_any<<<dim3(HE / 64, E / 64, 1), blk, 0, stream>>>(Wr[1], WkT, HE, E, flag);
    transpose_any<<<dim3(HE / 64, E / 64, 1), blk, 0, stream>>>(Wr[2], WvT, HE, E, flag);
    transpose_any<<<dim3(E / 64, HE / 64, 1), blk, 0, stream>>>(Wr[3], WoT, E, HE, flag);

    if (wsE >= needB2) {
        // ---- Tier B2': fused V-transpose in QKV-proj; exp-QK; L-in-PV ----
        bf16* QKb = p0;                  // [t, 8192] = Q|K; aliased for P later
        bf16* Vtb = QKb + wQK;           // [h,e,t] — written by MODE-4 epilogue
        bf16* S   = Vtb + wBat;          // exp(scores) [h,t,s]
        bf16* Oatt = S + sAll;           // O_all [M, HE]

        for (int b = 0; b < Bb; ++b) {
            const bf16* xb = xc + (size_t)b * T * E;
            // merged QKV projection; V columns written transposed to Vtb
            gemm_bt<4><<<dim3(N3 / 128, T / 128, 1), blk, 0, stream>>>(
                xb, WqT, QKb, bqc, E, E, N2, 0, 0, 0, E, qscale, HE, Vtb, N2);
            // QK: S = exp(Q K^T)
            gemm_bt<1><<<dim3(T / 128, T / 128, H), blk, 0, stream>>>(
                QKb, QKb + HE, S, nullptr, N2, N2, T,
                (long)E, (long)E, (long)T * T, E, 1.f, QC, nullptr, 0);
            // PV: O = (S V) / rowsum(S)
            gemm_bt<3><<<dim3(E / 128, T / 128, H), blk, 0, stream>>>(
                S, Vtb, Oatt + (size_t)b * T * HE, nullptr, T, T, HE,
                (long)T * T, (long)E * T, (long)E, T, 1.f, QC, nullptr, 0);
        }
        // out-proj: split-K=2, bf16 partials alias QKb (dead)
        gemm_bt_splitk<<<dim3(E / 128, M / 128, 2), blk, 0, stream>>>(
            Oatt, WoT, QKb, HE, HE, E, 0, 0, 0, (long)M * E, 2, HE / 2);
        reduce_emit<<<dim3((unsigned)((NX / 8 + 255) / 256)), blk, 0, stream>>>(
            QKb, boc, d_out, NX, E, flag);
        return;   // d_out written directly; no emit pass
    }

    if (wsE >= needB) {
        // ---- Tier B fallback: softmax path ----
        bf16* QKVb = p0;
        bf16* Vtb  = QKVb + wQKV;
        bf16* Oatt = Vtb + wBat;
        bf16* S    = Oatt + wBat;

        for (int b = 0; b < Bb; ++b) {
            const bf16* xb = xc + (size_t)b * T * E;
            gemm_bt<0><<<dim3(N3 / 128, T / 128, 1), blk, 0, stream>>>(
                xb, WqT, QKVb, bqc, E, E, N3, 0, 0, 0, E, qscale, HE, nullptr, 0);
            transpose_bf16<<<dim3(E / 64, T / 64, H), blk, 0, stream>>>(
                QKVb + 2 * HE, Vtb, N3, T, H, (long)E, (long)E * T, 0, 0);
            gemm_bt<0><<<dim3(T / 128, T / 128, H), blk, 0, stream>>>(
                QKVb, QKVb + HE, S, nullptr, N3, N3, T,
                (long)E, (long)E, (long)T * T, E, 1.f, QC, nullptr, 0);
            softmax_rows2048<<<dim3(H * T, 1, 1), blk, 0, stream>>>(S);
            gemm_bt<0><<<dim3(E / 128, T / 128, H), blk, 0, stream>>>(
                S, Vtb, Oatt, nullptr, T, T, HE,
                (long)T * T, (long)E * T, (long)E, T, 1.f, QC, nullptr, 0);
            gemm_bt_splitk<<<dim3(E / 128, T / 128, 8), blk, 0, stream>>>(
                Oatt, WoT, (bf16*)S, HE, HE, E, 0, 0, 0, (long)T * E, 8, HE / 8);
            reduce_splitk<<<dim3((unsigned)(((long)T * E / 8 + 255) / 256)), blk, 0, stream>>>(
                (bf16*)S, boc, Ofin + (size_t)b * T * E, (long)T * E, E, 8);
        }
    } else if (wsE >= needC) {
        // ---- Tier C fallback ----
        bf16* Qb  = p0;
        bf16* Kb  = Qb  + wBat;
        bf16* Vb  = Kb  + wBat;
        bf16* Vtb = Vb  + wBat;
        bf16* Ob  = Vtb + wBat;
        bf16* S   = Ob  + wBat;

        for (int b = 0; b < Bb; ++b) {
            const bf16* xb = xc + (size_t)b * T * E;
            gemm_bt<0><<<dim3(HE / 128, T / 128, 1), blk, 0, stream>>>(
                xb, WqT, Qb, bqc, E, E, HE, 0, 0, 0, E, qscale, QC, nullptr, 0);
            gemm_bt<0><<<dim3(HE / 128, T / 128, 1), blk, 0, stream>>>(
                xb, WkT, Kb, bkc, E, E, HE, 0, 0, 0, E, 1.f, QC, nullptr, 0);
            gemm_bt<0><<<dim3(HE / 128, T / 128, 1), blk, 0, stream>>>(
                xb, WvT, Vb, bvc, E, E, HE, 0, 0, 0, E, 1.f, QC, nullptr, 0);
            transpose_bf16<<<dim3(E / 64, T / 64, H), blk, 0, stream>>>(
                Vb, Vtb, HE, T, H, (long)E, (long)E * T, 0, 0);
            for (int h = 0; h < H; ++h) {
                gemm_bt<0><<<dim3(T / 128, T / 128, 1), blk, 0, stream>>>(
                    Qb + (size_t)h * E, Kb + (size_t)h * E, S, nullptr,
                    HE, HE, T, 0, 0, 0, E, 1.f, QC, nullptr, 0);
                softmax_rows2048<<<dim3(T, 1, 1), blk, 0, stream>>>(S);
                gemm_bt<0><<<dim3(E / 128, T / 128, 1), blk, 0, stream>>>(
                    S, Vtb + (size_t)h * E * T, Ob + (size_t)h * E, nullptr,
                    T, T, HE, 0, 0, 0, T, 1.f, QC, nullptr, 0);
            }
            gemm_bt<0><<<dim3(E / 128, T / 128, 1), blk, 0, stream>>>(
                Ob, WoT, Ofin + (size_t)b * T * E, boc,
                HE, HE, E, 0, 0, 0, HE, 1.f, QC, nullptr, 0);
        }
    } else {
        // ---- Tier D fallback ----
        bf16* Qh  = p0;
        bf16* Kh  = Qh  + wHd;
        bf16* Vh  = Kh  + wHd;
        bf16* Vth = Vh  + wHd;
        bf16* Oh  = Vth + wHd;
        bf16* S   = Oh  + wHd;

        for (int b = 0; b < Bb; ++b) {
            const bf16* xb = xc + (size_t)b * T * E;
            bf16* outb = Ofin + (size_t)b * T * E;
            for (int h = 0; h < H; ++h) {
                const size_t hw = (size_t)h * E * E;
                gemm_bt<0><<<dim3(E / 128, T / 128, 1), blk, 0, stream>>>(
                    xb, WqT + hw, Qh, bqc + (size_t)h * E, E, E, E,
                    0, 0, 0, E, qscale, QC, nullptr, 0);
                gemm_bt<0><<<dim3(E / 128, T / 128, 1), blk, 0, stream>>>(
                    xb, WkT + hw, Kh, bkc + (size_t)h * E, E, E, E,
                    0, 0, 0, E, 1.f, QC, nullptr, 0);
                gemm_bt<0><<<dim3(E / 128, T / 128, 1), blk, 0, stream>>>(
                    xb, WvT + hw, Vh, bvc + (size_t)h * E, E, E, E,
                    0, 0, 0, E, 1.f, QC, nullptr, 0);
                transpose_bf16<<<dim3(E / 64, T / 64, 1), blk, 0, stream>>>(
                    Vh, Vth, E, T, 1, 0, 0, 0, 0);
                gemm_bt<0><<<dim3(T / 128, T / 128, 1), blk, 0, stream>>>(
                    Qh, Kh, S, nullptr, E, E, T, 0, 0, 0, E, 1.f, QC, nullptr, 0);
                softmax_rows2048<<<dim3(T, 1, 1), blk, 0, stream>>>(S);
                gemm_bt<0><<<dim3(E / 128, T / 128, 1), blk, 0, stream>>>(
                    S, Vth, Oh, nullptr, T, T, E, 0, 0, 0, T, 1.f, QC, nullptr, 0);
                if (h == 0)
                    gemm_bt<0><<<dim3(E / 128, T / 128, 1), blk, 0, stream>>>(
                        Oh, WoT, outb, boc, E, HE, E, 0, 0, 0, E, 1.f, QC, nullptr, 0);
                else
                    gemm_bt<2><<<dim3(E / 128, T / 128, 1), blk, 0, stream>>>(
                        Oh, WoT + (size_t)h * E, outb, nullptr,
                        E, HE, E, 0, 0, 0, E, 1.f, QC, nullptr, 0);
            }
        }
    }

    // ---- emit in the probed dtype (fallback tiers only) ----
    emit_out<<<dim3((unsigned)((NX / 8 + 255) / 256)), blk, 0, stream>>>(
        Ofin, d_out, NX, flag);
}

// Round 10
// 918.653 us; speedup vs baseline: 1.2548x; 1.0343x over previous
//
#include <hip/hip_runtime.h>
#include <hip/hip_bf16.h>
#include <stdint.h>

typedef __hip_bfloat16 bf16;
typedef __bf16 bf16x8 __attribute__((ext_vector_type(8)));
typedef float floatx4 __attribute__((ext_vector_type(4)));

#define AS_LDS __attribute__((address_space(3)))
#define AS_GLB __attribute__((address_space(1)))

__device__ __forceinline__ void gload_lds16(const bf16* g, bf16* l) {
    __builtin_amdgcn_global_load_lds((const AS_GLB void*)g, (AS_LDS void*)l, 16, 0, 0);
}

// ---------- dtype probe: *flag = 1 if x is fp32, 0 if bf16 ----------
__global__ void probe_dtype(const float* __restrict__ x, int* __restrict__ flag) {
    __shared__ int cnt;
    if (threadIdx.x == 0) cnt = 0;
    __syncthreads();
    int ok = 0;
    for (int i = threadIdx.x; i < 4096; i += 256) {
        float v = x[i];
        if (v == v && fabsf(v) < 1.0e3f) ok++;
    }
    atomicAdd(&cnt, ok);
    __syncthreads();
    if (threadIdx.x == 0) *flag = (cnt > 2048) ? 1 : 0;
}

// ---------- convert raw (fp32 or bf16 per flag) -> canonical bf16 ----------
__global__ __launch_bounds__(256) void convert_to_bf16(
    const void* __restrict__ in, bf16* __restrict__ out, long n,
    const int* __restrict__ flag)
{
    long i = ((long)blockIdx.x * 256 + threadIdx.x) * 8;
    if (i >= n) return;
    bf16 o[8];
    if (*flag) {
        const float* p = (const float*)in + i;
        float4 a = *(const float4*)p;
        float4 b = *(const float4*)(p + 4);
        o[0] = __float2bfloat16(a.x); o[1] = __float2bfloat16(a.y);
        o[2] = __float2bfloat16(a.z); o[3] = __float2bfloat16(a.w);
        o[4] = __float2bfloat16(b.x); o[5] = __float2bfloat16(b.y);
        o[6] = __float2bfloat16(b.z); o[7] = __float2bfloat16(b.w);
    } else {
        *(float4*)o = *(const float4*)((const bf16*)in + i);
    }
    *(float4*)&out[i] = *(float4*)o;
}

// ---------- emit canonical bf16 -> d_out in flag dtype (fallback tiers) ----
__global__ __launch_bounds__(256) void emit_out(
    const bf16* __restrict__ in, void* __restrict__ out, long n,
    const int* __restrict__ flag)
{
    long i = ((long)blockIdx.x * 256 + threadIdx.x) * 8;
    if (i >= n) return;
    bf16 v[8];
    *(float4*)v = *(const float4*)&in[i];
    if (*flag) {
        float* o = (float*)out + i;
        float4 a, b;
        a.x = __bfloat162float(v[0]); a.y = __bfloat162float(v[1]);
        a.z = __bfloat162float(v[2]); a.w = __bfloat162float(v[3]);
        b.x = __bfloat162float(v[4]); b.y = __bfloat162float(v[5]);
        b.z = __bfloat162float(v[6]); b.w = __bfloat162float(v[7]);
        *(float4*)o = a;
        *(float4*)(o + 4) = b;
    } else {
        *(float4*)((bf16*)out + i) = *(float4*)v;
    }
}

// ---------- transpose raw-dtype input -> bf16 output ----------
__global__ __launch_bounds__(256) void transpose_any(
    const void* __restrict__ inv, bf16* __restrict__ out,
    int ldin, int ldout, const int* __restrict__ flag)
{
    __shared__ bf16 tile[64][80];
    const int fp32 = *flag;
    const int c0 = blockIdx.x * 64;
    const int r0 = blockIdx.y * 64;
    const int tid = threadIdx.x;
#pragma unroll
    for (int it = 0; it < 2; ++it) {
        int ch = tid + it * 256;
        int r = ch >> 3, c = (ch & 7) * 8;
        long eidx = (long)(r0 + r) * ldin + (c0 + c);
        if (fp32) {
            const float* p = (const float*)inv + eidx;
            float4 a = *(const float4*)p;
            float4 b = *(const float4*)(p + 4);
            bf16 o[8];
            o[0] = __float2bfloat16(a.x); o[1] = __float2bfloat16(a.y);
            o[2] = __float2bfloat16(a.z); o[3] = __float2bfloat16(a.w);
            o[4] = __float2bfloat16(b.x); o[5] = __float2bfloat16(b.y);
            o[6] = __float2bfloat16(b.z); o[7] = __float2bfloat16(b.w);
            *(float4*)&tile[r][c] = *(float4*)o;
        } else {
            *(float4*)&tile[r][c] = *(const float4*)((const bf16*)inv + eidx);
        }
    }
    __syncthreads();
#pragma unroll
    for (int it = 0; it < 2; ++it) {
        int ch = tid + it * 256;
        int oc = ch >> 3, rb = (ch & 7) * 8;
        bf16 tmp[8];
#pragma unroll
        for (int i = 0; i < 8; ++i) tmp[i] = tile[rb + i][oc];
        *(float4*)&out[(long)(c0 + oc) * ldout + r0 + rb] = *(float4*)tmp;
    }
}

// ---------- pure-bf16 transpose (fallback tiers) ----------
__global__ __launch_bounds__(256) void transpose_bf16(
    const bf16* __restrict__ in, bf16* __restrict__ out,
    int ldin, int ldout,
    int nz1, long in_z1, long out_z1, long in_z2, long out_z2)
{
    __shared__ bf16 tile[64][80];
    const int z = blockIdx.z;
    const int z1 = z % nz1, z2 = z / nz1;
    in  += (long)z1 * in_z1 + (long)z2 * in_z2;
    out += (long)z1 * out_z1 + (long)z2 * out_z2;
    const int c0 = blockIdx.x * 64;
    const int r0 = blockIdx.y * 64;
    const int tid = threadIdx.x;
#pragma unroll
    for (int it = 0; it < 2; ++it) {
        int ch = tid + it * 256;
        int r = ch >> 3, c = (ch & 7) * 8;
        *(float4*)&tile[r][c] = *(const float4*)&in[(long)(r0 + r) * ldin + c0 + c];
    }
    __syncthreads();
#pragma unroll
    for (int it = 0; it < 2; ++it) {
        int ch = tid + it * 256;
        int oc = ch >> 3, rb = (ch & 7) * 8;
        bf16 tmp[8];
#pragma unroll
        for (int i = 0; i < 8; ++i) tmp[i] = tile[rb + i][oc];
        *(float4*)&out[(long)(c0 + oc) * ldout + r0 + rb] = *(float4*)tmp;
    }
}

// ---------- GEMM (bf16 in/out, fp32 acc), templated epilogue -------------
// MODE 0: C = (acc + bias) * (col<qcols ? scale : 1)
// MODE 1: C = exp(acc)
// MODE 2: C += acc   (tier-D accumulate)
// MODE 3: C = acc / L, L = row-sum of A via ones-MFMA (K spans full row)
// MODE 4: QKV projection with fused V-transpose (see round 9)
// SWAP: x<->y grid swap. With gridDim.x = #m-tiles (multiple of 8) and
//       gridDim.y = #n-tiles, blocks sharing the same A row-block sit at
//       linear IDs gridDim.x apart -> same XCD under round-robin -> the
//       shared A rows are fetched from HBM once per XCD, served from L2.
template <int MODE, bool SWAP = false>
__global__ __launch_bounds__(256) void gemm_bt(
    const bf16* __restrict__ A, const bf16* __restrict__ Bt,
    bf16* __restrict__ C, const bf16* __restrict__ bias,
    int lda, int ldb, int ldc,
    long az, long bz, long cz, int K, float scale, int qcols,
    bf16* __restrict__ Vt, int vcol0)
{
    __shared__ bf16 As[128 * 64];
    __shared__ bf16 Bs[128 * 64];

    const int tid  = threadIdx.x;
    const int lane = tid & 63;
    const int wave = tid >> 6;
    const int wx = wave & 1;
    const int wy = wave >> 1;
    const long zz = blockIdx.z;
    A  += zz * az;
    Bt += zz * bz;
    C  += zz * cz;
    const int bm = SWAP ? blockIdx.x : blockIdx.y;
    const int bn = SWAP ? blockIdx.y : blockIdx.x;
    const int m0 = bm * 128;
    const int n0 = bn * 128;

    const int lm = lane & 15;
    const int kq = (lane >> 4) * 8;

    floatx4 acc[4][4];
#pragma unroll
    for (int i = 0; i < 4; ++i)
#pragma unroll
        for (int j = 0; j < 4; ++j)
            acc[i][j] = (floatx4){0.f, 0.f, 0.f, 0.f};

    floatx4 accOnes[4];
    bf16x8 ones;
    if constexpr (MODE == 3) {
#pragma unroll
        for (int i = 0; i < 4; ++i) accOnes[i] = (floatx4){0.f, 0.f, 0.f, 0.f};
#pragma unroll
        for (int k = 0; k < 8; ++k) ones[k] = (__bf16)1.0f;
    }

    for (int kt = 0; kt < K; kt += 64) {
        __syncthreads();
#pragma unroll
        for (int it = 0; it < 4; ++it) {
            int ch = tid + it * 256;
            int r = ch >> 3;
            int c = (ch & 7) * 8;
            gload_lds16(A  + (long)(m0 + r) * lda + (kt + c), &As[ch * 8]);
            gload_lds16(Bt + (long)(n0 + r) * ldb + (kt + c), &Bs[ch * 8]);
        }
        __syncthreads();
#pragma unroll
        for (int kk = 0; kk < 64; kk += 32) {
            bf16x8 af[4], bfv[4];
#pragma unroll
            for (int i = 0; i < 4; ++i)
                af[i] = *(const bf16x8*)&As[(wy * 64 + i * 16 + lm) * 64 + kk + kq];
#pragma unroll
            for (int j = 0; j < 4; ++j)
                bfv[j] = *(const bf16x8*)&Bs[(wx * 64 + j * 16 + lm) * 64 + kk + kq];
#pragma unroll
            for (int i = 0; i < 4; ++i) {
#pragma unroll
                for (int j = 0; j < 4; ++j)
                    acc[i][j] = __builtin_amdgcn_mfma_f32_16x16x32_bf16(
                        af[i], bfv[j], acc[i][j], 0, 0, 0);
                if constexpr (MODE == 3)
                    accOnes[i] = __builtin_amdgcn_mfma_f32_16x16x32_bf16(
                        af[i], ones, accOnes[i], 0, 0, 0);
            }
        }
    }

    const int cr = (lane >> 4) * 4;
    if constexpr (MODE == 1) {
#pragma unroll
        for (int j = 0; j < 4; ++j) {
            int col = n0 + wx * 64 + j * 16 + lm;
#pragma unroll
            for (int i = 0; i < 4; ++i)
#pragma unroll
                for (int r = 0; r < 4; ++r) {
                    int row = m0 + wy * 64 + i * 16 + cr + r;
                    C[(long)row * ldc + col] = __float2bfloat16(__expf(acc[i][j][r]));
                }
        }
    } else if constexpr (MODE == 3) {
        floatx4 inv[4];
#pragma unroll
        for (int i = 0; i < 4; ++i)
#pragma unroll
            for (int r = 0; r < 4; ++r)
                inv[i][r] = 1.0f / accOnes[i][r];
#pragma unroll
        for (int j = 0; j < 4; ++j) {
            int col = n0 + wx * 64 + j * 16 + lm;
#pragma unroll
            for (int i = 0; i < 4; ++i)
#pragma unroll
                for (int r = 0; r < 4; ++r) {
                    int row = m0 + wy * 64 + i * 16 + cr + r;
                    C[(long)row * ldc + col] =
                        __float2bfloat16(acc[i][j][r] * inv[i][r]);
                }
        }
    } else if constexpr (MODE == 4) {
        if (n0 >= vcol0) {
            // V block: write transposed, packed 4 consecutive t per 8B store
#pragma unroll
            for (int j = 0; j < 4; ++j) {
                int col = n0 + wx * 64 + j * 16 + lm;
                float bv = __bfloat162float(bias[col]);
                int eg = col - vcol0;
                bf16* vt = Vt + ((long)(eg >> 9) * 512 + (eg & 511)) * 2048;
#pragma unroll
                for (int i = 0; i < 4; ++i) {
                    int t0 = m0 + wy * 64 + i * 16 + cr;
                    bf16 pk[4];
#pragma unroll
                    for (int r = 0; r < 4; ++r)
                        pk[r] = __float2bfloat16(acc[i][j][r] + bv);
                    *(ushort4*)&vt[t0] = *(ushort4*)pk;
                }
            }
        } else {
#pragma unroll
            for (int j = 0; j < 4; ++j) {
                int col = n0 + wx * 64 + j * 16 + lm;
                float bv = __bfloat162float(bias[col]);
                float sc = (col < qcols) ? scale : 1.0f;
#pragma unroll
                for (int i = 0; i < 4; ++i)
#pragma unroll
                    for (int r = 0; r < 4; ++r) {
                        int row = m0 + wy * 64 + i * 16 + cr + r;
                        C[(long)row * ldc + col] =
                            __float2bfloat16((acc[i][j][r] + bv) * sc);
                    }
            }
        }
    } else {
#pragma unroll
        for (int j = 0; j < 4; ++j) {
            int col = n0 + wx * 64 + j * 16 + lm;
            float bv = (MODE == 0 && bias) ? __bfloat162float(bias[col]) : 0.f;
            float sc = (col < qcols) ? scale : 1.0f;
#pragma unroll
            for (int i = 0; i < 4; ++i) {
#pragma unroll
                for (int r = 0; r < 4; ++r) {
                    int row = m0 + wy * 64 + i * 16 + cr + r;
                    long idx = (long)row * ldc + col;
                    float v;
                    if (MODE == 2) v = acc[i][j][r] + __bfloat162float(C[idx]);
                    else           v = (acc[i][j][r] + bv) * sc;
                    C[idx] = __float2bfloat16(v);
                }
            }
        }
    }
}

// ---------- split-K GEMM, bf16 partials (SWAP as above) ------------------
template <bool SWAP = false>
__global__ __launch_bounds__(256) void gemm_bt_splitk(
    const bf16* __restrict__ A, const bf16* __restrict__ Bt,
    bf16* __restrict__ P, int lda, int ldb, int ldp,
    long az, long bz, long pz, long skStride, int nsk, int Kc)
{
    __shared__ bf16 As[128 * 64];
    __shared__ bf16 Bs[128 * 64];

    const int tid  = threadIdx.x;
    const int lane = tid & 63;
    const int wave = tid >> 6;
    const int wx = wave & 1;
    const int wy = wave >> 1;
    const int zz = blockIdx.z;
    const int ks = zz % nsk;
    const int zh = zz / nsk;
    A  += (long)zh * az;
    Bt += (long)zh * bz;
    bf16* Pz = P + (long)zh * pz + (long)ks * skStride;
    const int bm = SWAP ? blockIdx.x : blockIdx.y;
    const int bn = SWAP ? blockIdx.y : blockIdx.x;
    const int m0 = bm * 128;
    const int n0 = bn * 128;
    const int k0 = ks * Kc;

    const int lm = lane & 15;
    const int kq = (lane >> 4) * 8;

    floatx4 acc[4][4];
#pragma unroll
    for (int i = 0; i < 4; ++i)
#pragma unroll
        for (int j = 0; j < 4; ++j)
            acc[i][j] = (floatx4){0.f, 0.f, 0.f, 0.f};

    for (int kt = k0; kt < k0 + Kc; kt += 64) {
        __syncthreads();
#pragma unroll
        for (int it = 0; it < 4; ++it) {
            int ch = tid + it * 256;
            int r = ch >> 3;
            int c = (ch & 7) * 8;
            gload_lds16(A  + (long)(m0 + r) * lda + (kt + c), &As[ch * 8]);
            gload_lds16(Bt + (long)(n0 + r) * ldb + (kt + c), &Bs[ch * 8]);
        }
        __syncthreads();
#pragma unroll
        for (int kk = 0; kk < 64; kk += 32) {
            bf16x8 af[4], bfv[4];
#pragma unroll
            for (int i = 0; i < 4; ++i)
                af[i] = *(const bf16x8*)&As[(wy * 64 + i * 16 + lm) * 64 + kk + kq];
#pragma unroll
            for (int j = 0; j < 4; ++j)
                bfv[j] = *(const bf16x8*)&Bs[(wx * 64 + j * 16 + lm) * 64 + kk + kq];
#pragma unroll
            for (int i = 0; i < 4; ++i)
#pragma unroll
                for (int j = 0; j < 4; ++j)
                    acc[i][j] = __builtin_amdgcn_mfma_f32_16x16x32_bf16(
                        af[i], bfv[j], acc[i][j], 0, 0, 0);
        }
    }

    const int cr = (lane >> 4) * 4;
#pragma unroll
    for (int j = 0; j < 4; ++j) {
        int col = n0 + wx * 64 + j * 16 + lm;
#pragma unroll
        for (int i = 0; i < 4; ++i)
#pragma unroll
            for (int r = 0; r < 4; ++r) {
                int row = m0 + wy * 64 + i * 16 + cr + r;
                Pz[(long)row * ldp + col] = __float2bfloat16(acc[i][j][r]);
            }
    }
}

// ---------- reduce 2 bf16 split-K partials + bias -> d_out in flag dtype ----
__global__ __launch_bounds__(256) void reduce_emit(
    const bf16* __restrict__ P, const bf16* __restrict__ bias,
    void* __restrict__ out, long MN, int N,
    const int* __restrict__ flag)
{
    long i = ((long)blockIdx.x * 256 + threadIdx.x) * 8;
    if (i >= MN) return;
    bf16 bb[8], a[8], b[8];
    *(float4*)bb = *(const float4*)&bias[i & (N - 1)];
    *(float4*)a  = *(const float4*)&P[i];
    *(float4*)b  = *(const float4*)&P[MN + i];
    float s[8];
#pragma unroll
    for (int k = 0; k < 8; ++k)
        s[k] = __bfloat162float(bb[k]) + __bfloat162float(a[k]) + __bfloat162float(b[k]);
    if (*flag) {
        float* o = (float*)out + i;
        float4 lo = {s[0], s[1], s[2], s[3]};
        float4 hi = {s[4], s[5], s[6], s[7]};
        *(float4*)o = lo;
        *(float4*)(o + 4) = hi;
    } else {
        bf16 o[8];
#pragma unroll
        for (int k = 0; k < 8; ++k) o[k] = __float2bfloat16(s[k]);
        *(float4*)&((bf16*)out)[i] = *(float4*)o;
    }
}

// ---------- reduce bf16 split-K partials + bias -> bf16 (fallback) ----------
__global__ __launch_bounds__(256) void reduce_splitk(
    const bf16* __restrict__ P, const bf16* __restrict__ bias,
    bf16* __restrict__ Out, long MN, int N, int SK)
{
    long i = ((long)blockIdx.x * 256 + threadIdx.x) * 8;
    if (i >= MN) return;
    float s[8];
    if (bias) {
        bf16 bb[8];
        *(float4*)bb = *(const float4*)&bias[i & (N - 1)];
#pragma unroll
        for (int k = 0; k < 8; ++k) s[k] = __bfloat162float(bb[k]);
    } else {
#pragma unroll
        for (int k = 0; k < 8; ++k) s[k] = 0.f;
    }
    for (int z = 0; z < SK; ++z) {
        bf16 a[8];
        *(float4*)a = *(const float4*)&P[(long)z * MN + i];
#pragma unroll
        for (int k = 0; k < 8; ++k) s[k] += __bfloat162float(a[k]);
    }
    bf16 o[8];
#pragma unroll
    for (int k = 0; k < 8; ++k) o[k] = __float2bfloat16(s[k]);
    *(float4*)&Out[i] = *(float4*)o;
}

// ---------- in-place softmax over rows of 2048 bf16 (fallback tiers) -----
__global__ __launch_bounds__(256) void softmax_rows2048(bf16* __restrict__ S)
{
    __shared__ float red[8];
    const long row = blockIdx.x;
    bf16* p = S + row * 2048;
    const int tid = threadIdx.x;
    float4 raw = *(const float4*)&p[tid * 8];
    bf16 vb[8];
    *(float4*)vb = raw;
    float v[8];
#pragma unroll
    for (int i = 0; i < 8; ++i) v[i] = __bfloat162float(vb[i]);
    float m = v[0];
#pragma unroll
    for (int i = 1; i < 8; ++i) m = fmaxf(m, v[i]);
#pragma unroll
    for (int o = 32; o > 0; o >>= 1) m = fmaxf(m, __shfl_xor(m, o));
    if ((tid & 63) == 0) red[tid >> 6] = m;
    __syncthreads();
    m = fmaxf(fmaxf(red[0], red[1]), fmaxf(red[2], red[3]));
    float s = 0.f;
#pragma unroll
    for (int i = 0; i < 8; ++i) { v[i] = __expf(v[i] - m); s += v[i]; }
#pragma unroll
    for (int o = 32; o > 0; o >>= 1) s += __shfl_xor(s, o);
    if ((tid & 63) == 0) red[4 + (tid >> 6)] = s;
    __syncthreads();
    s = (red[4] + red[5]) + (red[6] + red[7]);
    float inv = 1.f / s;
#pragma unroll
    for (int i = 0; i < 8; ++i) vb[i] = __float2bfloat16(v[i] * inv);
    *(float4*)&p[tid * 8] = *(float4*)vb;
}

extern "C" void kernel_launch(void* const* d_in, const int* in_sizes, int n_in,
                              void* d_out, int out_size, void* d_ws, size_t ws_size,
                              hipStream_t stream)
{
    const int Bb = 4, T = 2048, E = 512, H = 8;
    const int HE = H * E;            // 4096
    const int N3 = 3 * HE;           // 12288
    const int N2 = 2 * HE;           // 8192 (Q|K row width)
    const int M  = Bb * T;           // 8192
    const long NX = (long)M * E;     // 4,194,304

    // ---- size-signature input assignment (order-robust) ----
    const void* xr = nullptr;
    const void* Wr[4] = {nullptr, nullptr, nullptr, nullptr};
    const void* br[3] = {nullptr, nullptr, nullptr};
    const void* bor = nullptr;
    int nw = 0, nb = 0;
    for (int i = 0; i < n_in; ++i) {
        int s = in_sizes[i];
        if      (s == (int)NX)      xr = d_in[i];
        else if (s == E * HE)       { if (nw < 4) Wr[nw++] = d_in[i]; }
        else if (s == HE)           { if (nb < 3) br[nb++] = d_in[i]; }
        else if (s == E)            bor = d_in[i];
    }
    if (!xr || nw < 4 || nb < 3 || !bor) {
        xr = d_in[0]; Wr[0] = d_in[1]; br[0] = d_in[2]; Wr[1] = d_in[3];
        br[1] = d_in[4]; Wr[2] = d_in[5]; br[2] = d_in[6]; Wr[3] = d_in[7];
        bor = d_in[8];
    }

    const float qscale = 0.04419417382415922f;  // 1/sqrt(512)
    const int   QC = 1 << 30;
    dim3 blk(256);

    // ---- workspace layout (bf16 elements) ----
    bf16* pool = (bf16*)d_ws;
    int*  flag = (int*)(void*)pool;
    bf16* xc   = pool + 8;
    bf16* bqc  = xc  + NX;     // bq|bk|bv contiguous (stacked bias [12288])
    bf16* bkc  = bqc + HE;
    bf16* bvc  = bkc + HE;
    bf16* boc  = bvc + HE;
    bf16* WqT  = boc + E;      // WqT|WkT|WvT contiguous (stacked Bt [12288,512])
    const size_t w2m = (size_t)E * HE;
    bf16* WkT  = WqT + w2m;
    bf16* WvT  = WkT + w2m;
    bf16* WoT  = WvT + w2m;
    bf16* Ofin = WoT + w2m;
    bf16* p0   = Ofin + NX;    // tier region

    const size_t wsE    = ws_size / sizeof(bf16);
    const size_t fixedE = (size_t)(p0 - pool);
    const size_t wQK   = (size_t)T * N2;      // 16.8M el — per-batch Q|K
    const size_t wQKV  = (size_t)T * N3;      // 25.17M el (tier-B fallback)
    const size_t wBat  = (size_t)T * HE;      // 8.39M el
    const size_t wHd   = (size_t)T * E;       // 1.05M el
    const size_t sAll  = (size_t)H * T * T;   // 33.55M el
    const size_t sOne  = (size_t)T * T;
    const size_t wBig  = (size_t)M * HE;      // 33.55M el
    const size_t needB2 = fixedE + wQK + wBat + sAll + wBig;   // ~218 MB
    const size_t needB  = fixedE + wQKV + 2 * wBat + sAll;     // ~185 MB
    const size_t needC  = fixedE + 5 * wBat + sOne;
    const size_t needD  = fixedE + 5 * wHd  + sOne;
    if (wsE < needD) return;

    // ---- stage 0: dtype probe + canonicalize ----
    probe_dtype<<<dim3(1), blk, 0, stream>>>((const float*)xr, flag);
    convert_to_bf16<<<dim3((unsigned)((NX / 8 + 255) / 256)), blk, 0, stream>>>(
        xr, xc, NX, flag);
    convert_to_bf16<<<dim3(2), blk, 0, stream>>>(br[0], bqc, HE, flag);
    convert_to_bf16<<<dim3(2), blk, 0, stream>>>(br[1], bkc, HE, flag);
    convert_to_bf16<<<dim3(2), blk, 0, stream>>>(br[2], bvc, HE, flag);
    convert_to_bf16<<<dim3(1), blk, 0, stream>>>(bor, boc, E, flag);
    transpose_any<<<dim3(HE / 64, E / 64, 1), blk, 0, stream>>>(Wr[0], WqT, HE, E, flag);
    transpose_any<<<dim3(HE / 64, E / 64, 1), blk, 0, stream>>>(Wr[1], WkT, HE, E, flag);
    transpose_any<<<dim3(HE / 64, E / 64, 1), blk, 0, stream>>>(Wr[2], WvT, HE, E, flag);
    transpose_any<<<dim3(E / 64, HE / 64, 1), blk, 0, stream>>>(Wr[3], WoT, E, HE, flag);

    if (wsE >= needB2) {
        // ---- Tier B2': fused V-transpose; exp-QK; L-in-PV; XCD-swapped PV ----
        bf16* QKb = p0;                  // [t, 8192] = Q|K; aliased for P later
        bf16* Vtb = QKb + wQK;           // [h,e,t] — written by MODE-4 epilogue
        bf16* S   = Vtb + wBat;          // exp(scores) [h,t,s]
        bf16* Oatt = S + sAll;           // O_all [M, HE]

        for (int b = 0; b < Bb; ++b) {
            const bf16* xb = xc + (size_t)b * T * E;
            // merged QKV projection; V columns written transposed to Vtb
            gemm_bt<4><<<dim3(N3 / 128, T / 128, 1), blk, 0, stream>>>(
                xb, WqT, QKb, bqc, E, E, N2, 0, 0, 0, E, qscale, HE, Vtb, N2);
            // QK: S = exp(Q K^T)  (symmetric M=N; no swap)
            gemm_bt<1><<<dim3(T / 128, T / 128, H), blk, 0, stream>>>(
                QKb, QKb + HE, S, nullptr, N2, N2, T,
                (long)E, (long)E, (long)T * T, E, 1.f, QC, nullptr, 0);
            // PV: O = (S V) / rowsum(S). SWAP grid: x=m-tiles(16), y=n-tiles(4)
            // -> 4 blocks sharing an S row-block are 16 apart -> same XCD.
            gemm_bt<3, true><<<dim3(T / 128, E / 128, H), blk, 0, stream>>>(
                S, Vtb, Oatt + (size_t)b * T * HE, nullptr, T, T, HE,
                (long)T * T, (long)E * T, (long)E, T, 1.f, QC, nullptr, 0);
        }
        // out-proj: split-K=2, SWAP grid: x=m-tiles(64), y=n-tiles(4)
        gemm_bt_splitk<true><<<dim3(M / 128, E / 128, 2), blk, 0, stream>>>(
            Oatt, WoT, QKb, HE, HE, E, 0, 0, 0, (long)M * E, 2, HE / 2);
        reduce_emit<<<dim3((unsigned)((NX / 8 + 255) / 256)), blk, 0, stream>>>(
            QKb, boc, d_out, NX, E, flag);
        return;   // d_out written directly; no emit pass
    }

    if (wsE >= needB) {
        // ---- Tier B fallback: softmax path ----
        bf16* QKVb = p0;
        bf16* Vtb  = QKVb + wQKV;
        bf16* Oatt = Vtb + wBat;
        bf16* S    = Oatt + wBat;

        for (int b = 0; b < Bb; ++b) {
            const bf16* xb = xc + (size_t)b * T * E;
            gemm_bt<0><<<dim3(N3 / 128, T / 128, 1), blk, 0, stream>>>(
                xb, WqT, QKVb, bqc, E, E, N3, 0, 0, 0, E, qscale, HE, nullptr, 0);
            transpose_bf16<<<dim3(E / 64, T / 64, H), blk, 0, stream>>>(
                QKVb + 2 * HE, Vtb, N3, T, H, (long)E, (long)E * T, 0, 0);
            gemm_bt<0><<<dim3(T / 128, T / 128, H), blk, 0, stream>>>(
                QKVb, QKVb + HE, S, nullptr, N3, N3, T,
                (long)E, (long)E, (long)T * T, E, 1.f, QC, nullptr, 0);
            softmax_rows2048<<<dim3(H * T, 1, 1), blk, 0, stream>>>(S);
            gemm_bt<0><<<dim3(E / 128, T / 128, H), blk, 0, stream>>>(
                S, Vtb, Oatt, nullptr, T, T, HE,
                (long)T * T, (long)E * T, (long)E, T, 1.f, QC, nullptr, 0);
            gemm_bt_splitk<false><<<dim3(E / 128, T / 128, 8), blk, 0, stream>>>(
                Oatt, WoT, (bf16*)S, HE, HE, E, 0, 0, 0, (long)T * E, 8, HE / 8);
            reduce_splitk<<<dim3((unsigned)(((long)T * E / 8 + 255) / 256)), blk, 0, stream>>>(
                (bf16*)S, boc, Ofin + (size_t)b * T * E, (long)T * E, E, 8);
        }
    } else if (wsE >= needC) {
        // ---- Tier C fallback ----
        bf16* Qb  = p0;
        bf16* Kb  = Qb  + wBat;
        bf16* Vb  = Kb  + wBat;
        bf16* Vtb = Vb  + wBat;
        bf16* Ob  = Vtb + wBat;
        bf16* S   = Ob  + wBat;

        for (int b = 0; b < Bb; ++b) {
            const bf16* xb = xc + (size_t)b * T * E;
            gemm_bt<0><<<dim3(HE / 128, T / 128, 1), blk, 0, stream>>>(
                xb, WqT, Qb, bqc, E, E, HE, 0, 0, 0, E, qscale, QC, nullptr, 0);
            gemm_bt<0><<<dim3(HE / 128, T / 128, 1), blk, 0, stream>>>(
                xb, WkT, Kb, bkc, E, E, HE, 0, 0, 0, E, 1.f, QC, nullptr, 0);
            gemm_bt<0><<<dim3(HE / 128, T / 128, 1), blk, 0, stream>>>(
                xb, WvT, Vb, bvc, E, E, HE, 0, 0, 0, E, 1.f, QC, nullptr, 0);
            transpose_bf16<<<dim3(E / 64, T / 64, H), blk, 0, stream>>>(
                Vb, Vtb, HE, T, H, (long)E, (long)E * T, 0, 0);
            for (int h = 0; h < H; ++h) {
                gemm_bt<0><<<dim3(T / 128, T / 128, 1), blk, 0, stream>>>(
                    Qb + (size_t)h * E, Kb + (size_t)h * E, S, nullptr,
                    HE, HE, T, 0, 0, 0, E, 1.f, QC, nullptr, 0);
                softmax_rows2048<<<dim3(T, 1, 1), blk, 0, stream>>>(S);
                gemm_bt<0><<<dim3(E / 128, T / 128, 1), blk, 0, stream>>>(
                    S, Vtb + (size_t)h * E * T, Ob + (size_t)h * E, nullptr,
                    T, T, HE, 0, 0, 0, T, 1.f, QC, nullptr, 0);
            }
            gemm_bt<0><<<dim3(E / 128, T / 128, 1), blk, 0, stream>>>(
                Ob, WoT, Ofin + (size_t)b * T * E, boc,
                HE, HE, E, 0, 0, 0, HE, 1.f, QC, nullptr, 0);
        }
    } else {
        // ---- Tier D fallback ----
        bf16* Qh  = p0;
        bf16* Kh  = Qh  + wHd;
        bf16* Vh  = Kh  + wHd;
        bf16* Vth = Vh  + wHd;
        bf16* Oh  = Vth + wHd;
        bf16* S   = Oh  + wHd;

        for (int b = 0; b < Bb; ++b) {
            const bf16* xb = xc + (size_t)b * T * E;
            bf16* outb = Ofin + (size_t)b * T * E;
            for (int h = 0; h < H; ++h) {
                const size_t hw = (size_t)h * E * E;
                gemm_bt<0><<<dim3(E / 128, T / 128, 1), blk, 0, stream>>>(
                    xb, WqT + hw, Qh, bqc + (size_t)h * E, E, E, E,
                    0, 0, 0, E, qscale, QC, nullptr, 0);
                gemm_bt<0><<<dim3(E / 128, T / 128, 1), blk, 0, stream>>>(
                    xb, WkT + hw, Kh, bkc + (size_t)h * E, E, E, E,
                    0, 0, 0, E, 1.f, QC, nullptr, 0);
                gemm_bt<0><<<dim3(E / 128, T / 128, 1), blk, 0, stream>>>(
                    xb, WvT + hw, Vh, bvc + (size_t)h * E, E, E, E,
                    0, 0, 0, E, 1.f, QC, nullptr, 0);
                transpose_bf16<<<dim3(E / 64, T / 64, 1), blk, 0, stream>>>(
                    Vh, Vth, E, T, 1, 0, 0, 0, 0);
                gemm_bt<0><<<dim3(T / 128, T / 128, 1), blk, 0, stream>>>(
                    Qh, Kh, S, nullptr, E, E, T, 0, 0, 0, E, 1.f, QC, nullptr, 0);
                softmax_rows2048<<<dim3(T, 1, 1), blk, 0, stream>>>(S);
                gemm_bt<0><<<dim3(E / 128, T / 128, 1), blk, 0, stream>>>(
                    S, Vth, Oh, nullptr, T, T, E, 0, 0, 0, T, 1.f, QC, nullptr, 0);
                if (h == 0)
                    gemm_bt<0><<<dim3(E / 128, T / 128, 1), blk, 0, stream>>>(
                        Oh, WoT, outb, boc, E, HE, E, 0, 0, 0, E, 1.f, QC, nullptr, 0);
                else
                    gemm_bt<2><<<dim3(E / 128, T / 128, 1), blk, 0, stream>>>(
                        Oh, WoT + (size_t)h * E, outb, nullptr,
                        E, HE, E, 0, 0, 0, E, 1.f, QC, nullptr, 0);
            }
        }
    }

    // ---- emit in the probed dtype (fallback tiers only) ----
    emit_out<<<dim3((unsigned)((NX / 8 + 255) / 256)), blk, 0, stream>>>(
        Ofin, d_out, NX, flag);
}